// Round 1
// baseline (8371.440 us; speedup 1.0000x reference)
//
#include <hip/hip_runtime.h>
#include <cstdint>

#define T_LEN 2048
#define NTOK  4096      // B*T
#define DIMF  512
#define NHASH 8
#define NBUK  32        // buckets per hash round
#define NCHUNK 256      // NHASH * NBUK
#define SELF_VAL -5e4f

// ---------------------------------------------------------------- conv + pe
__global__ __launch_bounds__(256) void k_conv_pe(
    const float* __restrict__ spec, const float* __restrict__ w,
    const float* __restrict__ bias, const float* __restrict__ pe_row,
    const float* __restrict__ pe_col, float* __restrict__ x1, float* __restrict__ x2) {
  int m = blockIdx.x; int b = m >> 11; int t = m & 2047;
  __shared__ float s3[3 * 229];
  for (int idx = threadIdx.x; idx < 687; idx += 256) {
    int k = idx / 229, i = idx - k * 229;
    int tt = t + k - 1;
    s3[idx] = (tt >= 0 && tt < T_LEN) ? spec[((long)b * T_LEN + tt) * 229 + i] : 0.f;
  }
  __syncthreads();
  for (int o = threadIdx.x; o < 512; o += 256) {
    float acc = bias[o];
    const float* wo_ = w + (long)o * 687;   // (i,k) contiguous per o
    for (int k = 0; k < 3; ++k) {
      const float* sk = s3 + k * 229;
      for (int i = 0; i < 229; ++i) acc += sk[i] * wo_[i * 3 + k];
    }
    float xv = fmaxf(acc, 0.f);
    xv += (o < 256) ? pe_row[(t >> 6) * 256 + o] : pe_col[(t & 63) * 256 + (o - 256)];
    long oi = (long)m * 512 + o;
    x1[oi] = xv; x2[oi] = xv;
  }
}

// ---------------------------------------------------------------- layernorm
__global__ __launch_bounds__(256) void k_ln(
    const float* __restrict__ x, const float* __restrict__ g,
    const float* __restrict__ bb, float* __restrict__ out) {
  int row = blockIdx.x, tid = threadIdx.x;
  const float* xr = x + (long)row * 512;
  float v0 = xr[tid], v1 = xr[tid + 256];
  float s1 = v0 + v1, s2 = v0 * v0 + v1 * v1;
  #pragma unroll
  for (int off = 1; off < 64; off <<= 1) { s1 += __shfl_xor(s1, off); s2 += __shfl_xor(s2, off); }
  __shared__ float r1[4], r2[4];
  int w = tid >> 6, lane = tid & 63;
  if (lane == 0) { r1[w] = s1; r2[w] = s2; }
  __syncthreads();
  float S1 = r1[0] + r1[1] + r1[2] + r1[3];
  float S2 = r2[0] + r2[1] + r2[2] + r2[3];
  float mean = S1 * (1.f / 512.f);
  float var  = S2 * (1.f / 512.f) - mean * mean;
  float rstd = 1.f / sqrtf(var + 1e-5f);
  out[(long)row * 512 + tid]       = (v0 - mean) * rstd * g[tid] + bb[tid];
  out[(long)row * 512 + tid + 256] = (v1 - mean) * rstd * g[tid + 256] + bb[tid + 256];
}

// ---------------------------------------------------------------- SGEMM
// C[M,N] = f( A[M,K] @ B[K,N] ), BM=BN=64, BK=16, 256 thr, 4x4 micro-tile.
// MAP: 0 = row-major C (stride N), 1 = per-head scatter for qk/v buffers.
template<int MAP, int RES, int BIAS, int GELU, int HALF>
__global__ __launch_bounds__(256) void k_gemm(
    const float* __restrict__ A, const float* __restrict__ A2,
    const float* __restrict__ B, const float* __restrict__ bias,
    float* __restrict__ C, int M, int N, int K) {
  __shared__ float As[16][64];   // transposed: As[k][m]
  __shared__ float Bs[16][64];
  int tid = threadIdx.x;
  int n0 = blockIdx.x * 64, m0 = blockIdx.y * 64;
  int tx = tid & 15, ty = tid >> 4;
  int ar = tid >> 2, ac = tid & 3;    // A staging
  int bkr = tid >> 4, bc = tid & 15;  // B staging
  float acc[4][4] = {};
  for (int k0 = 0; k0 < K; k0 += 16) {
    float4 av = *(const float4*)(A + (long)(m0 + ar) * K + k0 + ac * 4);
    if (HALF) {
      float4 av2 = *(const float4*)(A2 + (long)(m0 + ar) * K + k0 + ac * 4);
      av.x = 0.5f * (av.x + av2.x); av.y = 0.5f * (av.y + av2.y);
      av.z = 0.5f * (av.z + av2.z); av.w = 0.5f * (av.w + av2.w);
    }
    As[ac * 4 + 0][ar] = av.x; As[ac * 4 + 1][ar] = av.y;
    As[ac * 4 + 2][ar] = av.z; As[ac * 4 + 3][ar] = av.w;
    int bn = n0 + bc * 4;
    float4 bv;
    if (bn + 3 < N) {
      bv = *(const float4*)(B + (long)(k0 + bkr) * N + bn);
    } else {
      float tmp[4];
      #pragma unroll
      for (int jj = 0; jj < 4; ++jj)
        tmp[jj] = (bn + jj < N) ? B[(long)(k0 + bkr) * N + bn + jj] : 0.f;
      bv.x = tmp[0]; bv.y = tmp[1]; bv.z = tmp[2]; bv.w = tmp[3];
    }
    *(float4*)&Bs[bkr][bc * 4] = bv;
    __syncthreads();
    #pragma unroll
    for (int kk = 0; kk < 16; ++kk) {
      float4 a = *(const float4*)&As[kk][ty * 4];
      float4 b = *(const float4*)&Bs[kk][tx * 4];
      acc[0][0] += a.x * b.x; acc[0][1] += a.x * b.y; acc[0][2] += a.x * b.z; acc[0][3] += a.x * b.w;
      acc[1][0] += a.y * b.x; acc[1][1] += a.y * b.y; acc[1][2] += a.y * b.z; acc[1][3] += a.y * b.w;
      acc[2][0] += a.z * b.x; acc[2][1] += a.z * b.y; acc[2][2] += a.z * b.z; acc[2][3] += a.z * b.w;
      acc[3][0] += a.w * b.x; acc[3][1] += a.w * b.y; acc[3][2] += a.w * b.z; acc[3][3] += a.w * b.w;
    }
    __syncthreads();
  }
  #pragma unroll
  for (int i = 0; i < 4; ++i) {
    int m = m0 + ty * 4 + i;
    #pragma unroll
    for (int j = 0; j < 4; ++j) {
      int n = n0 + tx * 4 + j;
      if (n >= N) continue;
      float v = acc[i][j];
      if (BIAS) v += bias[n];
      if (GELU) v = 0.5f * v * (1.f + erff(v * 0.70710678118654752f));
      long idx;
      if (MAP == 1) {
        int b = m >> 11, t = m & 2047, hh = n >> 6, dd = n & 63;
        idx = (((long)(b * 8 + hh)) * T_LEN + t) * 64 + dd;
      } else {
        idx = (long)m * N + n;
      }
      if (RES) v += C[idx];
      C[idx] = v;
    }
  }
}

// ---------------------------------------------------------------- LSH hashing
// grid: bh(16) * ttile(64); block 256 = 32 tokens x 8 hash rounds
__global__ __launch_bounds__(256) void k_hash(
    const float* __restrict__ qk, const float* __restrict__ rot,
    int* __restrict__ buckets) {
  int bhid = blockIdx.x >> 6; int t0 = (blockIdx.x & 63) * 32;
  __shared__ float qrow[32][64];
  __shared__ float rl[64][8][20];   // padded to kill bank conflicts
  for (int idx = threadIdx.x; idx < 32 * 64; idx += 256) {
    int tok = idx >> 6, f = idx & 63;
    qrow[tok][f] = qk[((long)bhid * T_LEN + t0 + tok) * 64 + f];
  }
  for (int idx = threadIdx.x; idx < 64 * 128; idx += 256) {
    int f = idx >> 7, rem = idx & 127, hh = rem >> 4, ii = rem & 15;
    rl[f][hh][ii] = rot[idx];
  }
  __syncthreads();
  int tok = threadIdx.x >> 3, h = threadIdx.x & 7;
  float acc[16] = {};
  for (int f = 0; f < 64; ++f) {
    float qv = qrow[tok][f];
    #pragma unroll
    for (int i = 0; i < 16; ++i) acc[i] += qv * rl[f][h][i];
  }
  float best = acc[0]; int bi = 0;
  #pragma unroll
  for (int i = 1; i < 16; ++i) if (acc[i] > best) { best = acc[i]; bi = i; }
  #pragma unroll
  for (int i = 0; i < 16; ++i) if (-acc[i] > best) { best = -acc[i]; bi = 16 + i; }
  buckets[((long)bhid * 8 + h) * T_LEN + t0 + tok] = bi;
}

// ---------------------------------------------------------------- stable counting sort
// One block per (bh, hash). Stable sort of 2048 positions by bucket (32 bins).
// st[bh, h*2048 + sortedIdx] = original position.
__global__ __launch_bounds__(256) void k_sort(
    const int* __restrict__ buckets, int* __restrict__ st) {
  int bh = blockIdx.x >> 3, h = blockIdx.x & 7;
  const int* bk = buckets + ((long)bh * 8 + h) * T_LEN;
  __shared__ unsigned char lb[2048];
  __shared__ int hist[32], cnt[32];
  __shared__ int whist[4][32];
  if (threadIdx.x < 32) hist[threadIdx.x] = 0;
  __syncthreads();
  for (int p = threadIdx.x; p < 2048; p += 256) {
    int v = bk[p]; lb[p] = (unsigned char)v; atomicAdd(&hist[v], 1);
  }
  __syncthreads();
  if (threadIdx.x == 0) {
    int run = 0;
    for (int i = 0; i < 32; ++i) { cnt[i] = run; run += hist[i]; }
  }
  __syncthreads();
  int lane = threadIdx.x & 63, w = threadIdx.x >> 6;
  unsigned long long mlt = (1ull << lane) - 1ull;
  int* outp = st + (long)bh * (NHASH * T_LEN) + h * T_LEN;
  for (int tile = 0; tile < 8; ++tile) {
    int p = tile * 256 + threadIdx.x;
    int myb = lb[p];
    int wrank = 0;
    for (int bv = 0; bv < 32; ++bv) {
      unsigned long long mm = __ballot(myb == bv);
      if (myb == bv) wrank = __popcll(mm & mlt);
      if (lane == bv) whist[w][bv] = __popcll(mm);
    }
    __syncthreads();
    int off = cnt[myb];
    for (int w2 = 0; w2 < w; ++w2) off += whist[w2][myb];
    outp[off + wrank] = p;
    __syncthreads();
    if (threadIdx.x < 32)
      cnt[threadIdx.x] += whist[0][threadIdx.x] + whist[1][threadIdx.x] +
                          whist[2][threadIdx.x] + whist[3][threadIdx.x];
    __syncthreads();
  }
}

// ---------------------------------------------------------------- chunked attention
// grid: bh(16) * chunk(256); block 512. Gathers rows via st, computes
// dots -> masked softmax (exact LSE) -> PV, scatters out rows to (h, orig pos).
__global__ __launch_bounds__(512) void k_attn(
    const float* __restrict__ qk, const float* __restrict__ vv,
    const int* __restrict__ st, float* __restrict__ o, float* __restrict__ lg) {
  __shared__ float Qt[64][68];    // [f][q]  (unnormalized Q)
  __shared__ float Kt[64][132];   // [f][k]  (normalized K, own+prev chunk)
  __shared__ float Vs[128][64];   // [k][d]
  __shared__ float Ds[128][68];   // [k][q]  dots, then p
  __shared__ int   kpos[128];     // 0..63 own chunk, 64..127 prev chunk
  int bh = blockIdx.x >> 8, c = blockIdx.x & 255;
  int h = c >> 5, cp = (c + 255) & 255;
  int tid = threadIdx.x, lane = tid & 63, w = tid >> 6;
  const int* stb = st + (long)bh * (NHASH * T_LEN);
  if (tid < 128) kpos[tid] = stb[((tid < 64) ? c : cp) * 64 + (tid & 63)];
  __syncthreads();
  const float* qkb = qk + (long)bh * T_LEN * 64;
  const float* vvb = vv + (long)bh * T_LEN * 64;
  for (int r = w; r < 64; r += 8) Qt[lane][r] = qkb[(long)kpos[r] * 64 + lane];
  for (int r = w; r < 128; r += 8) {
    float val = qkb[(long)kpos[r] * 64 + lane];
    float s2 = val * val;
    #pragma unroll
    for (int off = 1; off < 64; off <<= 1) s2 += __shfl_xor(s2, off);
    float nrm = fmaxf(sqrtf(s2), 1e-12f);
    Kt[lane][r] = val / nrm;
    Vs[r][lane] = vvb[(long)kpos[r] * 64 + lane];
  }
  __syncthreads();
  { // dots: 64q x 128k, K=64.  16 q-tiles x 32 k-tiles, 4x4 each.
    int qt = tid >> 5, kt = tid & 31;
    int q0 = qt * 4, k0 = kt * 4;
    float acc[4][4] = {};
    #pragma unroll 4
    for (int kk = 0; kk < 64; ++kk) {
      float4 a = *(const float4*)&Qt[kk][q0];
      float4 b = *(const float4*)&Kt[kk][k0];
      acc[0][0] += a.x * b.x; acc[0][1] += a.x * b.y; acc[0][2] += a.x * b.z; acc[0][3] += a.x * b.w;
      acc[1][0] += a.y * b.x; acc[1][1] += a.y * b.y; acc[1][2] += a.y * b.z; acc[1][3] += a.y * b.w;
      acc[2][0] += a.z * b.x; acc[2][1] += a.z * b.y; acc[2][2] += a.z * b.z; acc[2][3] += a.z * b.w;
      acc[3][0] += a.w * b.x; acc[3][1] += a.w * b.y; acc[3][2] += a.w * b.z; acc[3][3] += a.w * b.w;
    }
    int qp0 = kpos[q0], qp1 = kpos[q0 + 1], qp2 = kpos[q0 + 2], qp3 = kpos[q0 + 3];
    #pragma unroll
    for (int j = 0; j < 4; ++j) {
      int kp = kpos[k0 + j];
      float4 dv;
      dv.x = (qp0 == kp) ? SELF_VAL : acc[0][j] * 0.125f;
      dv.y = (qp1 == kp) ? SELF_VAL : acc[1][j] * 0.125f;
      dv.z = (qp2 == kp) ? SELF_VAL : acc[2][j] * 0.125f;
      dv.w = (qp3 == kp) ? SELF_VAL : acc[3][j] * 0.125f;
      *(float4*)&Ds[k0 + j][q0] = dv;
    }
  }
  __syncthreads();
  { // softmax over 128 keys per q-row; 8 threads per row
    int q = tid >> 3, s = tid & 7;
    float vals[16]; float mx = -3.4e38f;
    #pragma unroll
    for (int j = 0; j < 16; ++j) { vals[j] = Ds[s + 8 * j][q]; mx = fmaxf(mx, vals[j]); }
    mx = fmaxf(mx, __shfl_xor(mx, 1));
    mx = fmaxf(mx, __shfl_xor(mx, 2));
    mx = fmaxf(mx, __shfl_xor(mx, 4));
    float sm = 0.f; float ev[16];
    #pragma unroll
    for (int j = 0; j < 16; ++j) { ev[j] = expf(vals[j] - mx); sm += ev[j]; }
    sm += __shfl_xor(sm, 1); sm += __shfl_xor(sm, 2); sm += __shfl_xor(sm, 4);
    float inv = 1.f / sm;
    #pragma unroll
    for (int j = 0; j < 16; ++j) Ds[s + 8 * j][q] = ev[j] * inv;
    if (s == 0) lg[((long)bh * 8 + h) * T_LEN + kpos[q]] = mx + logf(sm);
  }
  __syncthreads();
  { // PV: out 64q x 64d, K=128.  32 q-tiles(x2) x 16 d-tiles(x4)
    int qt = tid >> 4, dt = tid & 15;
    int q0 = qt * 2, d0 = dt * 4;
    float a00 = 0, a01 = 0, a02 = 0, a03 = 0;
    float a10 = 0, a11 = 0, a12 = 0, a13 = 0;
    #pragma unroll 4
    for (int kk = 0; kk < 128; ++kk) {
      float2 a = *(const float2*)&Ds[kk][q0];
      float4 b = *(const float4*)&Vs[kk][d0];
      a00 += a.x * b.x; a01 += a.x * b.y; a02 += a.x * b.z; a03 += a.x * b.w;
      a10 += a.y * b.x; a11 += a.y * b.y; a12 += a.y * b.z; a13 += a.y * b.w;
    }
    long ob = ((long)bh * 8 + h) * T_LEN;
    *(float4*)&o[(ob + kpos[q0]) * 64 + d0]     = make_float4(a00, a01, a02, a03);
    *(float4*)&o[(ob + kpos[q0 + 1]) * 64 + d0] = make_float4(a10, a11, a12, a13);
  }
}

// ---------------------------------------------------------------- combine hash rounds
__global__ __launch_bounds__(256) void k_combine(
    const float* __restrict__ o, const float* __restrict__ lg, float* __restrict__ att) {
  int m = blockIdx.x; int b = m >> 11, t = m & 2047;
  int head = threadIdx.x >> 5, d0 = (threadIdx.x & 31) * 2;
  int bh = b * 8 + head;
  const float* lgp = lg + (long)bh * 8 * T_LEN + t;
  float l[8], mx = -3.4e38f;
  #pragma unroll
  for (int hh = 0; hh < 8; ++hh) { l[hh] = lgp[(long)hh * T_LEN]; mx = fmaxf(mx, l[hh]); }
  float sm = 0.f;
  #pragma unroll
  for (int hh = 0; hh < 8; ++hh) { l[hh] = expf(l[hh] - mx); sm += l[hh]; }
  float inv = 1.f / sm;
  float a0 = 0.f, a1 = 0.f;
  #pragma unroll
  for (int hh = 0; hh < 8; ++hh) {
    const float* op = o + (((long)bh * 8 + hh) * T_LEN + t) * 64 + d0;
    float w_ = l[hh] * inv;
    a0 += w_ * op[0]; a1 += w_ * op[1];
  }
  float* ap = att + (long)m * 512 + head * 64 + d0;
  ap[0] = a0; ap[1] = a1;
}

// ---------------------------------------------------------------- host
extern "C" void kernel_launch(void* const* d_in, const int* in_sizes, int n_in,
                              void* d_out, int out_size, void* d_ws, size_t ws_size,
                              hipStream_t stream) {
  const float* spec   = (const float*)d_in[0];
  const float* conv_w = (const float*)d_in[1];
  const float* conv_b = (const float*)d_in[2];
  const float* pe_row = (const float*)d_in[3];
  const float* pe_col = (const float*)d_in[4];
  const float* lnA_g  = (const float*)d_in[5];
  const float* lnA_b  = (const float*)d_in[6];
  const float* wqk    = (const float*)d_in[7];
  const float* wv     = (const float*)d_in[8];
  const float* wo     = (const float*)d_in[9];
  const float* bo     = (const float*)d_in[10];
  const float* lnF_g  = (const float*)d_in[11];
  const float* lnF_b  = (const float*)d_in[12];
  const float* w1     = (const float*)d_in[13];
  const float* b1     = (const float*)d_in[14];
  const float* w2     = (const float*)d_in[15];
  const float* b2     = (const float*)d_in[16];
  const float* lin_w  = (const float*)d_in[17];
  const float* lin_b  = (const float*)d_in[18];
  const float* rot    = (const float*)d_in[19];

  float* ws = (float*)d_ws;
  const long TOKF = (long)NTOK * 512;            // 2,097,152
  float* x1  = ws;
  float* x2  = ws + TOKF;
  float* xn  = ws + 2 * TOKF;
  float* qkb = ws + 3 * TOKF;
  float* vvb = ws + 4 * TOKF;
  float* att = ws + 5 * TOKF;
  float* h1  = ws + 6 * TOKF;                    // 4096 x 2048
  float* o   = h1 + (long)NTOK * 2048;           // 16 x 8 x 2048 x 64
  float* lg  = o + (long)16 * 8 * T_LEN * 64;    // 16 x 8 x 2048
  int*   stx = (int*)(lg + (long)16 * 8 * T_LEN);
  int*   buckets = stx + (long)16 * NHASH * T_LEN;

  dim3 g512(8, 64);    // N=512 GEMMs
  dim3 gffn1(32, 64);  // N=2048
  dim3 glin(2, 64);    // N=88

  k_conv_pe<<<NTOK, 256, 0, stream>>>(spec, conv_w, conv_b, pe_row, pe_col, x1, x2);

  for (int l = 0; l < 8; ++l) {
    const long W2 = (long)l * 512 * 512;
    k_ln<<<NTOK, 256, 0, stream>>>(x2, lnA_g + l * 512, lnA_b + l * 512, xn);
    k_gemm<1,0,0,0,0><<<g512, 256, 0, stream>>>(xn, nullptr, wqk + W2, nullptr, qkb, NTOK, 512, 512);
    k_gemm<1,0,0,0,0><<<g512, 256, 0, stream>>>(xn, nullptr, wv  + W2, nullptr, vvb, NTOK, 512, 512);
    k_hash<<<1024, 256, 0, stream>>>(qkb, rot + (long)l * 8192, buckets);
    k_sort<<<128, 256, 0, stream>>>(buckets, stx);
    k_attn<<<4096, 512, 0, stream>>>(qkb, vvb, stx, o, lg);
    k_combine<<<NTOK, 256, 0, stream>>>(o, lg, att);
    k_gemm<0,1,1,0,0><<<g512, 256, 0, stream>>>(att, nullptr, wo + W2, bo + l * 512, x1, NTOK, 512, 512);
    k_ln<<<NTOK, 256, 0, stream>>>(x1, lnF_g + l * 512, lnF_b + l * 512, xn);
    k_gemm<0,0,1,1,0><<<gffn1, 256, 0, stream>>>(xn, nullptr, w1 + (long)l * 512 * 2048,
                                                 b1 + (long)l * 2048, h1, NTOK, 2048, 512);
    k_gemm<0,1,1,0,0><<<g512, 256, 0, stream>>>(h1, nullptr, w2 + (long)l * 2048 * 512,
                                                b2 + l * 512, x2, NTOK, 512, 2048);
  }
  k_gemm<0,0,1,0,1><<<glin, 256, 0, stream>>>(x1, x2, lin_w, lin_b, (float*)d_out, NTOK, 88, 512);
}

// Round 3
// 5147.841 us; speedup vs baseline: 1.6262x; 1.6262x over previous
//
#include <hip/hip_runtime.h>
#include <hip/hip_bf16.h>
#include <cstdint>

#define T_LEN 2048
#define NTOK  4096      // B*T
#define NHASH 8
#define NBUK  32
#define SELF_VAL -5e4f

typedef __attribute__((ext_vector_type(8))) short short8v;
typedef __attribute__((ext_vector_type(4))) float f32x4;

// ---------------------------------------------------------------- im2col (conv k=3 pad=1), K padded to 688
__global__ __launch_bounds__(256) void k_im2col(
    const float* __restrict__ spec, float* __restrict__ col) {
  int m = blockIdx.x; int b = m >> 11, t = m & 2047;
  for (int c = threadIdx.x; c < 688; c += 256) {
    float v = 0.f;
    if (c < 687) {
      int k = (c >= 458) ? 2 : (c >= 229 ? 1 : 0);
      int i = c - k * 229;
      int tt = t + k - 1;
      if (tt >= 0 && tt < T_LEN) v = spec[((long)b * T_LEN + tt) * 229 + i];
    }
    col[(long)m * 688 + c] = v;
  }
}

// conv weight repack: Bc[c=k*229+i][o] = w[o][i][k]; row 687 zero
__global__ __launch_bounds__(256) void k_wconv(
    const float* __restrict__ w, float* __restrict__ Bc) {
  int c = blockIdx.x;
  int k = (c >= 458) ? 2 : (c >= 229 ? 1 : 0);
  int i = c - k * 229;
  for (int o = threadIdx.x; o < 512; o += 256) {
    float v = (c < 687) ? w[((long)o * 229 + i) * 3 + k] : 0.f;
    Bc[(long)c * 512 + o] = v;
  }
}

// add positional embedding, duplicate stream
__global__ __launch_bounds__(256) void k_pe(
    const float* __restrict__ pe_row, const float* __restrict__ pe_col,
    float* __restrict__ x1, float* __restrict__ x2) {
  int m = blockIdx.x, t = m & 2047;
  for (int o = threadIdx.x; o < 512; o += 256) {
    long idx = (long)m * 512 + o;
    float v = x1[idx] + ((o < 256) ? pe_row[(t >> 6) * 256 + o]
                                   : pe_col[(t & 63) * 256 + (o - 256)]);
    x1[idx] = v; x2[idx] = v;
  }
}

// ---------------------------------------------------------------- layernorm (OUTB: bf16 out for MFMA path)
template<int OUTB>
__global__ __launch_bounds__(256) void k_ln(
    const float* __restrict__ x, const float* __restrict__ g,
    const float* __restrict__ bb, float* __restrict__ out,
    __hip_bfloat16* __restrict__ outb) {
  int row = blockIdx.x, tid = threadIdx.x;
  const float* xr = x + (long)row * 512;
  float v0 = xr[tid], v1 = xr[tid + 256];
  float s1 = v0 + v1, s2 = v0 * v0 + v1 * v1;
  #pragma unroll
  for (int off = 1; off < 64; off <<= 1) { s1 += __shfl_xor(s1, off); s2 += __shfl_xor(s2, off); }
  __shared__ float r1[4], r2[4];
  int w = tid >> 6, lane = tid & 63;
  if (lane == 0) { r1[w] = s1; r2[w] = s2; }
  __syncthreads();
  float S1 = r1[0] + r1[1] + r1[2] + r1[3];
  float S2 = r2[0] + r2[1] + r2[2] + r2[3];
  float mean = S1 * (1.f / 512.f);
  float var  = S2 * (1.f / 512.f) - mean * mean;
  float rstd = 1.f / sqrtf(var + 1e-5f);
  float o0 = (v0 - mean) * rstd * g[tid] + bb[tid];
  float o1 = (v1 - mean) * rstd * g[tid + 256] + bb[tid + 256];
  if (OUTB) {
    outb[(long)row * 512 + tid]       = __float2bfloat16(o0);
    outb[(long)row * 512 + tid + 256] = __float2bfloat16(o1);
  } else {
    out[(long)row * 512 + tid]       = o0;
    out[(long)row * 512 + tid + 256] = o1;
  }
}

// ---------------------------------------------------------------- f32 SGEMM (qk/v/wo/conv/lin)
template<int MAP, int RES, int BIAS, int RELU, int HALF>
__global__ __launch_bounds__(256) void k_gemm(
    const float* __restrict__ A, const float* __restrict__ A2,
    const float* __restrict__ B, const float* __restrict__ bias,
    float* __restrict__ C, int M, int N, int K) {
  __shared__ float As[16][64];
  __shared__ float Bs[16][64];
  int tid = threadIdx.x;
  int n0 = blockIdx.x * 64, m0 = blockIdx.y * 64;
  int tx = tid & 15, ty = tid >> 4;
  int ar = tid >> 2, ac = tid & 3;
  int bkr = tid >> 4, bc = tid & 15;
  float acc[4][4] = {};
  for (int k0 = 0; k0 < K; k0 += 16) {
    float4 av = *(const float4*)(A + (long)(m0 + ar) * K + k0 + ac * 4);
    if (HALF) {
      float4 av2 = *(const float4*)(A2 + (long)(m0 + ar) * K + k0 + ac * 4);
      av.x = 0.5f * (av.x + av2.x); av.y = 0.5f * (av.y + av2.y);
      av.z = 0.5f * (av.z + av2.z); av.w = 0.5f * (av.w + av2.w);
    }
    As[ac * 4 + 0][ar] = av.x; As[ac * 4 + 1][ar] = av.y;
    As[ac * 4 + 2][ar] = av.z; As[ac * 4 + 3][ar] = av.w;
    int bn = n0 + bc * 4;
    float4 bv;
    if (bn + 3 < N) {
      bv = *(const float4*)(B + (long)(k0 + bkr) * N + bn);
    } else {
      float tmp[4];
      #pragma unroll
      for (int jj = 0; jj < 4; ++jj)
        tmp[jj] = (bn + jj < N) ? B[(long)(k0 + bkr) * N + bn + jj] : 0.f;
      bv.x = tmp[0]; bv.y = tmp[1]; bv.z = tmp[2]; bv.w = tmp[3];
    }
    *(float4*)&Bs[bkr][bc * 4] = bv;
    __syncthreads();
    #pragma unroll
    for (int kk = 0; kk < 16; ++kk) {
      float4 a = *(const float4*)&As[kk][ty * 4];
      float4 b = *(const float4*)&Bs[kk][tx * 4];
      acc[0][0] += a.x * b.x; acc[0][1] += a.x * b.y; acc[0][2] += a.x * b.z; acc[0][3] += a.x * b.w;
      acc[1][0] += a.y * b.x; acc[1][1] += a.y * b.y; acc[1][2] += a.y * b.z; acc[1][3] += a.y * b.w;
      acc[2][0] += a.z * b.x; acc[2][1] += a.z * b.y; acc[2][2] += a.z * b.z; acc[2][3] += a.z * b.w;
      acc[3][0] += a.w * b.x; acc[3][1] += a.w * b.y; acc[3][2] += a.w * b.z; acc[3][3] += a.w * b.w;
    }
    __syncthreads();
  }
  #pragma unroll
  for (int i = 0; i < 4; ++i) {
    int m = m0 + ty * 4 + i;
    #pragma unroll
    for (int j = 0; j < 4; ++j) {
      int n = n0 + tx * 4 + j;
      if (n >= N) continue;
      float v = acc[i][j];
      if (BIAS) v += bias[n];
      if (RELU) v = fmaxf(v, 0.f);
      long idx;
      if (MAP == 1) {
        int b = m >> 11, t = m & 2047, hh = n >> 6, dd = n & 63;
        idx = (((long)(b * 8 + hh)) * T_LEN + t) * 64 + dd;
      } else {
        idx = (long)m * N + n;
      }
      if (RES) v += C[idx];
      C[idx] = v;
    }
  }
}

// ---------------------------------------------------------------- bf16 MFMA GEMM (FFN)
// A: [M][K] bf16, Bt: [N][K] bf16 (pre-transposed). LDS stride padded to 40 (2-way free).
template<int BM, int BN, int WM, int WN, int GELU, int RES>
__global__ __launch_bounds__(256) void k_mgemm(
    const ushort* __restrict__ A, const ushort* __restrict__ Bt,
    const float* __restrict__ bias, __hip_bfloat16* __restrict__ Cb,
    float* __restrict__ Cf, int M, int N, int K) {
  constexpr int MF = WM / 16, NF = WN / 16;
  constexpr int NWC = BN / WN;
  __shared__ ushort As[BM * 40];
  __shared__ ushort Bs[BN * 40];
  int tid = threadIdx.x;
  int m0 = blockIdx.y * BM, n0 = blockIdx.x * BN;
  int wid = tid >> 6, lane = tid & 63;
  int wr = wid / NWC, wc = wid % NWC;
  int r = lane & 15, kg = lane >> 4;
  f32x4 acc[MF][NF] = {};
  for (int k0 = 0; k0 < K; k0 += 32) {
    __syncthreads();
    for (int idx = tid; idx < BM * 4; idx += 256) {
      int row = idx >> 2, kq = idx & 3;
      *(short8v*)&As[row * 40 + kq * 8] =
          *(const short8v*)(A + (long)(m0 + row) * K + k0 + kq * 8);
    }
    for (int idx = tid; idx < BN * 4; idx += 256) {
      int row = idx >> 2, kq = idx & 3;
      *(short8v*)&Bs[row * 40 + kq * 8] =
          *(const short8v*)(Bt + (long)(n0 + row) * K + k0 + kq * 8);
    }
    __syncthreads();
    short8v af[MF], bf[NF];
    #pragma unroll
    for (int i = 0; i < MF; ++i)
      af[i] = *(const short8v*)&As[(wr * WM + i * 16 + r) * 40 + kg * 8];
    #pragma unroll
    for (int j = 0; j < NF; ++j)
      bf[j] = *(const short8v*)&Bs[(wc * WN + j * 16 + r) * 40 + kg * 8];
    #pragma unroll
    for (int i = 0; i < MF; ++i)
      #pragma unroll
      for (int j = 0; j < NF; ++j)
        acc[i][j] = __builtin_amdgcn_mfma_f32_16x16x32_bf16(af[i], bf[j], acc[i][j], 0, 0, 0);
  }
  #pragma unroll
  for (int i = 0; i < MF; ++i) {
    int mb = m0 + wr * WM + i * 16 + (lane >> 4) * 4;
    #pragma unroll
    for (int j = 0; j < NF; ++j) {
      int n = n0 + wc * WN + j * 16 + r;
      float bv = bias[n];
      #pragma unroll
      for (int q = 0; q < 4; ++q) {
        float v = acc[i][j][q] + bv;
        if (GELU) v = 0.5f * v * (1.f + erff(v * 0.70710678118654752f));
        long idx = (long)(mb + q) * N + n;
        if (RES) Cf[idx] += v;
        else Cb[idx] = __float2bfloat16(v);
      }
    }
  }
}

// tiled transpose + f32->bf16 convert: dst[c][r] = bf16(src[r][c]); src R x C
__global__ __launch_bounds__(256) void k_tcvt(
    const float* __restrict__ src, __hip_bfloat16* __restrict__ dst, int R, int C) {
  __shared__ float tile[32][33];
  int c0 = blockIdx.x * 32, r0 = blockIdx.y * 32;
  int tx = threadIdx.x & 31, ty = threadIdx.x >> 5;
  #pragma unroll
  for (int i = 0; i < 4; ++i)
    tile[ty + i * 8][tx] = src[(long)(r0 + ty + i * 8) * C + c0 + tx];
  __syncthreads();
  #pragma unroll
  for (int i = 0; i < 4; ++i)
    dst[(long)(c0 + ty + i * 8) * R + r0 + tx] = __float2bfloat16(tile[tx][ty + i * 8]);
}

// ---------------------------------------------------------------- LSH hashing
__global__ __launch_bounds__(256) void k_hash(
    const float* __restrict__ qk, const float* __restrict__ rot,
    int* __restrict__ buckets) {
  int bhid = blockIdx.x >> 6; int t0 = (blockIdx.x & 63) * 32;
  __shared__ float qrow[32][64];
  __shared__ float rl[64][8][20];
  for (int idx = threadIdx.x; idx < 32 * 64; idx += 256) {
    int tok = idx >> 6, f = idx & 63;
    qrow[tok][f] = qk[((long)bhid * T_LEN + t0 + tok) * 64 + f];
  }
  for (int idx = threadIdx.x; idx < 64 * 128; idx += 256) {
    int f = idx >> 7, rem = idx & 127, hh = rem >> 4, ii = rem & 15;
    rl[f][hh][ii] = rot[idx];
  }
  __syncthreads();
  int tok = threadIdx.x >> 3, h = threadIdx.x & 7;
  float acc[16] = {};
  for (int f = 0; f < 64; ++f) {
    float qv = qrow[tok][f];
    #pragma unroll
    for (int i = 0; i < 16; ++i) acc[i] += qv * rl[f][h][i];
  }
  float best = acc[0]; int bi = 0;
  #pragma unroll
  for (int i = 1; i < 16; ++i) if (acc[i] > best) { best = acc[i]; bi = i; }
  #pragma unroll
  for (int i = 0; i < 16; ++i) if (-acc[i] > best) { best = -acc[i]; bi = 16 + i; }
  buckets[((long)bhid * 8 + h) * T_LEN + t0 + tok] = bi;
}

// ---------------------------------------------------------------- stable counting sort
__global__ __launch_bounds__(256) void k_sort(
    const int* __restrict__ buckets, int* __restrict__ st) {
  int bh = blockIdx.x >> 3, h = blockIdx.x & 7;
  const int* bk = buckets + ((long)bh * 8 + h) * T_LEN;
  __shared__ unsigned char lb[2048];
  __shared__ int hist[32], cnt[32];
  __shared__ int whist[4][32];
  if (threadIdx.x < 32) hist[threadIdx.x] = 0;
  __syncthreads();
  for (int p = threadIdx.x; p < 2048; p += 256) {
    int v = bk[p]; lb[p] = (unsigned char)v; atomicAdd(&hist[v], 1);
  }
  __syncthreads();
  if (threadIdx.x == 0) {
    int run = 0;
    for (int i = 0; i < 32; ++i) { cnt[i] = run; run += hist[i]; }
  }
  __syncthreads();
  int lane = threadIdx.x & 63, w = threadIdx.x >> 6;
  unsigned long long mlt = (1ull << lane) - 1ull;
  int* outp = st + (long)bh * (NHASH * T_LEN) + h * T_LEN;
  for (int tile = 0; tile < 8; ++tile) {
    int p = tile * 256 + threadIdx.x;
    int myb = lb[p];
    int wrank = 0;
    for (int bv = 0; bv < 32; ++bv) {
      unsigned long long mm = __ballot(myb == bv);
      if (myb == bv) wrank = __popcll(mm & mlt);
      if (lane == bv) whist[w][bv] = __popcll(mm);
    }
    __syncthreads();
    int off = cnt[myb];
    for (int w2 = 0; w2 < w; ++w2) off += whist[w2][myb];
    outp[off + wrank] = p;
    __syncthreads();
    if (threadIdx.x < 32)
      cnt[threadIdx.x] += whist[0][threadIdx.x] + whist[1][threadIdx.x] +
                          whist[2][threadIdx.x] + whist[3][threadIdx.x];
    __syncthreads();
  }
}

// ---------------------------------------------------------------- chunked attention
__global__ __launch_bounds__(512) void k_attn(
    const float* __restrict__ qk, const float* __restrict__ vv,
    const int* __restrict__ st, float* __restrict__ o, float* __restrict__ lg) {
  __shared__ float Qt[64][68];
  __shared__ float Kt[64][132];
  __shared__ float Vs[128][64];
  __shared__ float Ds[128][68];
  __shared__ int   kpos[128];
  int bh = blockIdx.x >> 8, c = blockIdx.x & 255;
  int h = c >> 5, cp = (c + 255) & 255;
  int tid = threadIdx.x, lane = tid & 63, w = tid >> 6;
  const int* stb = st + (long)bh * (NHASH * T_LEN);
  if (tid < 128) kpos[tid] = stb[((tid < 64) ? c : cp) * 64 + (tid & 63)];
  __syncthreads();
  const float* qkb = qk + (long)bh * T_LEN * 64;
  const float* vvb = vv + (long)bh * T_LEN * 64;
  for (int r = w; r < 64; r += 8) Qt[lane][r] = qkb[(long)kpos[r] * 64 + lane];
  for (int r = w; r < 128; r += 8) {
    float val = qkb[(long)kpos[r] * 64 + lane];
    float s2 = val * val;
    #pragma unroll
    for (int off = 1; off < 64; off <<= 1) s2 += __shfl_xor(s2, off);
    float nrm = fmaxf(sqrtf(s2), 1e-12f);
    Kt[lane][r] = val / nrm;
    Vs[r][lane] = vvb[(long)kpos[r] * 64 + lane];
  }
  __syncthreads();
  {
    int qt = tid >> 5, kt = tid & 31;
    int q0 = qt * 4, k0 = kt * 4;
    float acc[4][4] = {};
    #pragma unroll 4
    for (int kk = 0; kk < 64; ++kk) {
      float4 a = *(const float4*)&Qt[kk][q0];
      float4 b = *(const float4*)&Kt[kk][k0];
      acc[0][0] += a.x * b.x; acc[0][1] += a.x * b.y; acc[0][2] += a.x * b.z; acc[0][3] += a.x * b.w;
      acc[1][0] += a.y * b.x; acc[1][1] += a.y * b.y; acc[1][2] += a.y * b.z; acc[1][3] += a.y * b.w;
      acc[2][0] += a.z * b.x; acc[2][1] += a.z * b.y; acc[2][2] += a.z * b.z; acc[2][3] += a.z * b.w;
      acc[3][0] += a.w * b.x; acc[3][1] += a.w * b.y; acc[3][2] += a.w * b.z; acc[3][3] += a.w * b.w;
    }
    int qp0 = kpos[q0], qp1 = kpos[q0 + 1], qp2 = kpos[q0 + 2], qp3 = kpos[q0 + 3];
    #pragma unroll
    for (int j = 0; j < 4; ++j) {
      int kp = kpos[k0 + j];
      float4 dv;
      dv.x = (qp0 == kp) ? SELF_VAL : acc[0][j] * 0.125f;
      dv.y = (qp1 == kp) ? SELF_VAL : acc[1][j] * 0.125f;
      dv.z = (qp2 == kp) ? SELF_VAL : acc[2][j] * 0.125f;
      dv.w = (qp3 == kp) ? SELF_VAL : acc[3][j] * 0.125f;
      *(float4*)&Ds[k0 + j][q0] = dv;
    }
  }
  __syncthreads();
  {
    int q = tid >> 3, s = tid & 7;
    float vals[16]; float mx = -3.4e38f;
    #pragma unroll
    for (int j = 0; j < 16; ++j) { vals[j] = Ds[s + 8 * j][q]; mx = fmaxf(mx, vals[j]); }
    mx = fmaxf(mx, __shfl_xor(mx, 1));
    mx = fmaxf(mx, __shfl_xor(mx, 2));
    mx = fmaxf(mx, __shfl_xor(mx, 4));
    float sm = 0.f; float ev[16];
    #pragma unroll
    for (int j = 0; j < 16; ++j) { ev[j] = expf(vals[j] - mx); sm += ev[j]; }
    sm += __shfl_xor(sm, 1); sm += __shfl_xor(sm, 2); sm += __shfl_xor(sm, 4);
    float inv = 1.f / sm;
    #pragma unroll
    for (int j = 0; j < 16; ++j) Ds[s + 8 * j][q] = ev[j] * inv;
    if (s == 0) lg[((long)bh * 8 + h) * T_LEN + kpos[q]] = mx + logf(sm);
  }
  __syncthreads();
  {
    int qt = tid >> 4, dt = tid & 15;
    int q0 = qt * 2, d0 = dt * 4;
    float a00 = 0, a01 = 0, a02 = 0, a03 = 0;
    float a10 = 0, a11 = 0, a12 = 0, a13 = 0;
    #pragma unroll 4
    for (int kk = 0; kk < 128; ++kk) {
      float2 a = *(const float2*)&Ds[kk][q0];
      float4 b = *(const float4*)&Vs[kk][d0];
      a00 += a.x * b.x; a01 += a.x * b.y; a02 += a.x * b.z; a03 += a.x * b.w;
      a10 += a.y * b.x; a11 += a.y * b.y; a12 += a.y * b.z; a13 += a.y * b.w;
    }
    long ob = ((long)bh * 8 + h) * T_LEN;
    *(float4*)&o[(ob + kpos[q0]) * 64 + d0]     = make_float4(a00, a01, a02, a03);
    *(float4*)&o[(ob + kpos[q0 + 1]) * 64 + d0] = make_float4(a10, a11, a12, a13);
  }
}

// ---------------------------------------------------------------- combine hash rounds
__global__ __launch_bounds__(256) void k_combine(
    const float* __restrict__ o, const float* __restrict__ lg, float* __restrict__ att) {
  int m = blockIdx.x; int b = m >> 11, t = m & 2047;
  int head = threadIdx.x >> 5, d0 = (threadIdx.x & 31) * 2;
  int bh = b * 8 + head;
  const float* lgp = lg + (long)bh * 8 * T_LEN + t;
  float l[8], mx = -3.4e38f;
  #pragma unroll
  for (int hh = 0; hh < 8; ++hh) { l[hh] = lgp[(long)hh * T_LEN]; mx = fmaxf(mx, l[hh]); }
  float sm = 0.f;
  #pragma unroll
  for (int hh = 0; hh < 8; ++hh) { l[hh] = expf(l[hh] - mx); sm += l[hh]; }
  float inv = 1.f / sm;
  float a0 = 0.f, a1 = 0.f;
  #pragma unroll
  for (int hh = 0; hh < 8; ++hh) {
    const float* op = o + (((long)bh * 8 + hh) * T_LEN + t) * 64 + d0;
    float w_ = l[hh] * inv;
    a0 += w_ * op[0]; a1 += w_ * op[1];
  }
  float* ap = att + (long)m * 512 + head * 64 + d0;
  ap[0] = a0; ap[1] = a1;
}

// ---------------------------------------------------------------- host
extern "C" void kernel_launch(void* const* d_in, const int* in_sizes, int n_in,
                              void* d_out, int out_size, void* d_ws, size_t ws_size,
                              hipStream_t stream) {
  const float* spec   = (const float*)d_in[0];
  const float* conv_w = (const float*)d_in[1];
  const float* conv_b = (const float*)d_in[2];
  const float* pe_row = (const float*)d_in[3];
  const float* pe_col = (const float*)d_in[4];
  const float* lnA_g  = (const float*)d_in[5];
  const float* lnA_b  = (const float*)d_in[6];
  const float* wqk    = (const float*)d_in[7];
  const float* wv     = (const float*)d_in[8];
  const float* wo     = (const float*)d_in[9];
  const float* bo     = (const float*)d_in[10];
  const float* lnF_g  = (const float*)d_in[11];
  const float* lnF_b  = (const float*)d_in[12];
  const float* w1     = (const float*)d_in[13];
  const float* b1     = (const float*)d_in[14];
  const float* w2     = (const float*)d_in[15];
  const float* b2     = (const float*)d_in[16];
  const float* lin_w  = (const float*)d_in[17];
  const float* lin_b  = (const float*)d_in[18];
  const float* rot    = (const float*)d_in[19];

  float* ws = (float*)d_ws;
  const long TOKF = (long)NTOK * 512;
  float* x1  = ws;
  float* x2  = ws + TOKF;
  float* xn  = ws + 2 * TOKF;
  float* qkb = ws + 3 * TOKF;
  float* vvb = ws + 4 * TOKF;
  float* att = ws + 5 * TOKF;
  float* o   = ws + 6 * TOKF;                      // 16.78M floats
  float* lg  = o + (long)16 * 8 * T_LEN * 64;
  int*   stx = (int*)(lg + (long)16 * 8 * T_LEN);
  int*   buckets = stx + (long)16 * NHASH * T_LEN;
  __hip_bfloat16* xnb = (__hip_bfloat16*)(buckets + (long)16 * NHASH * T_LEN);
  float* h1region = (float*)(xnb + TOKF);          // max(colbuf 2.82M, h1b 4.19M) floats
  __hip_bfloat16* h1b = (__hip_bfloat16*)h1region;
  float* colbuf = h1region;                        // alias (conv happens first)
  float* w1region = h1region + (long)NTOK * 1024;  // 4.19M floats reserved
  __hip_bfloat16* w1b = (__hip_bfloat16*)w1region;
  float* Bc = w1region;                            // alias (conv first), needs 0.36M floats
  __hip_bfloat16* w2b = (__hip_bfloat16*)(w1region + (long)540672);  // after 0.54M floats

  dim3 g512(8, 64);
  dim3 glin(2, 64);

  // conv frontend as GEMM
  k_im2col<<<NTOK, 256, 0, stream>>>(spec, colbuf);
  k_wconv<<<688, 256, 0, stream>>>(conv_w, Bc);
  k_gemm<0,0,1,1,0><<<g512, 256, 0, stream>>>(colbuf, nullptr, Bc, conv_b, x1, NTOK, 512, 688);
  k_pe<<<NTOK, 256, 0, stream>>>(pe_row, pe_col, x1, x2);

  for (int l = 0; l < 8; ++l) {
    const long W2 = (long)l * 512 * 512;
    k_ln<0><<<NTOK, 256, 0, stream>>>(x2, lnA_g + l * 512, lnA_b + l * 512, xn, nullptr);
    k_gemm<1,0,0,0,0><<<g512, 256, 0, stream>>>(xn, nullptr, wqk + W2, nullptr, qkb, NTOK, 512, 512);
    k_gemm<1,0,0,0,0><<<g512, 256, 0, stream>>>(xn, nullptr, wv  + W2, nullptr, vvb, NTOK, 512, 512);
    k_hash<<<1024, 256, 0, stream>>>(qkb, rot + (long)l * 8192, buckets);
    k_sort<<<128, 256, 0, stream>>>(buckets, stx);
    k_attn<<<4096, 512, 0, stream>>>(qkb, vvb, stx, o, lg);
    k_combine<<<NTOK, 256, 0, stream>>>(o, lg, att);
    k_gemm<0,1,1,0,0><<<g512, 256, 0, stream>>>(att, nullptr, wo + W2, bo + l * 512, x1, NTOK, 512, 512);
    k_ln<1><<<NTOK, 256, 0, stream>>>(x1, lnF_g + l * 512, lnF_b + l * 512, nullptr, xnb);
    // FFN via bf16 MFMA
    k_tcvt<<<dim3(64, 16), 256, 0, stream>>>(w1 + (long)l * 512 * 2048, w1b, 512, 2048);
    k_mgemm<128,128,64,64,1,0><<<dim3(16, 32), 256, 0, stream>>>(
        (const ushort*)xnb, (const ushort*)w1b, b1 + (long)l * 2048, h1b, nullptr, NTOK, 2048, 512);
    k_tcvt<<<dim3(16, 64), 256, 0, stream>>>(w2 + (long)l * 2048 * 512, w2b, 2048, 512);
    k_mgemm<64,128,32,64,0,1><<<dim3(4, 64), 256, 0, stream>>>(
        (const ushort*)h1b, (const ushort*)w2b, b2 + (long)l * 512, nullptr, x2, NTOK, 512, 2048);
  }
  k_gemm<0,0,1,0,1><<<glin, 256, 0, stream>>>(x1, x2, lin_w, lin_b, (float*)d_out, NTOK, 88, 512);
}

// Round 4
// 2725.112 us; speedup vs baseline: 3.0720x; 1.8890x over previous
//
#include <hip/hip_runtime.h>
#include <hip/hip_fp16.h>
#include <cstdint>

#define T_LEN 2048
#define NTOK  4096      // B*T
#define NHASH 8
#define SELF_VAL -5e4f

typedef __attribute__((ext_vector_type(8))) short short8v;
typedef __attribute__((ext_vector_type(8))) _Float16 half8v;
typedef __attribute__((ext_vector_type(4))) float f32x4;
typedef __attribute__((ext_vector_type(4))) unsigned short ushort4v;

// ---------------------------------------------------------------- im2col (conv k=3 pad=1), K padded to 688
__global__ __launch_bounds__(256) void k_im2col(
    const float* __restrict__ spec, float* __restrict__ col) {
  int m = blockIdx.x; int b = m >> 11, t = m & 2047;
  for (int c = threadIdx.x; c < 688; c += 256) {
    float v = 0.f;
    if (c < 687) {
      int k = (c >= 458) ? 2 : (c >= 229 ? 1 : 0);
      int i = c - k * 229;
      int tt = t + k - 1;
      if (tt >= 0 && tt < T_LEN) v = spec[((long)b * T_LEN + tt) * 229 + i];
    }
    col[(long)m * 688 + c] = v;
  }
}

__global__ __launch_bounds__(256) void k_wconv(
    const float* __restrict__ w, float* __restrict__ Bc) {
  int c = blockIdx.x;
  int k = (c >= 458) ? 2 : (c >= 229 ? 1 : 0);
  int i = c - k * 229;
  for (int o = threadIdx.x; o < 512; o += 256) {
    float v = (c < 687) ? w[((long)o * 229 + i) * 3 + k] : 0.f;
    Bc[(long)c * 512 + o] = v;
  }
}

__global__ __launch_bounds__(256) void k_pe(
    const float* __restrict__ pe_row, const float* __restrict__ pe_col,
    float* __restrict__ x1, float* __restrict__ x2) {
  int m = blockIdx.x, t = m & 2047;
  for (int o = threadIdx.x; o < 512; o += 256) {
    long idx = (long)m * 512 + o;
    float v = x1[idx] + ((o < 256) ? pe_row[(t >> 6) * 256 + o]
                                   : pe_col[(t & 63) * 256 + (o - 256)]);
    x1[idx] = v; x2[idx] = v;
  }
}

// ---------------------------------------------------------------- layernorm; OUTB: 0=f32, 1=f16, 2=both
template<int OUTB>
__global__ __launch_bounds__(256) void k_ln(
    const float* __restrict__ x, const float* __restrict__ g,
    const float* __restrict__ bb, float* __restrict__ out,
    __half* __restrict__ outh) {
  int row = blockIdx.x, tid = threadIdx.x;
  const float* xr = x + (long)row * 512;
  float v0 = xr[tid], v1 = xr[tid + 256];
  float s1 = v0 + v1, s2 = v0 * v0 + v1 * v1;
  #pragma unroll
  for (int off = 1; off < 64; off <<= 1) { s1 += __shfl_xor(s1, off); s2 += __shfl_xor(s2, off); }
  __shared__ float r1[4], r2[4];
  int w = tid >> 6, lane = tid & 63;
  if (lane == 0) { r1[w] = s1; r2[w] = s2; }
  __syncthreads();
  float S1 = r1[0] + r1[1] + r1[2] + r1[3];
  float S2 = r2[0] + r2[1] + r2[2] + r2[3];
  float mean = S1 * (1.f / 512.f);
  float var  = S2 * (1.f / 512.f) - mean * mean;
  float rstd = 1.f / sqrtf(var + 1e-5f);
  float o0 = (v0 - mean) * rstd * g[tid] + bb[tid];
  float o1 = (v1 - mean) * rstd * g[tid + 256] + bb[tid + 256];
  if (OUTB != 1) {
    out[(long)row * 512 + tid]       = o0;
    out[(long)row * 512 + tid + 256] = o1;
  }
  if (OUTB >= 1) {
    outh[(long)row * 512 + tid]       = __float2half(o0);
    outh[(long)row * 512 + tid + 256] = __float2half(o1);
  }
}

// ---------------------------------------------------------------- f32 SGEMM (qk/conv/lin)
template<int MAP, int RES, int BIAS, int RELU, int HALF>
__global__ __launch_bounds__(256) void k_gemm(
    const float* __restrict__ A, const float* __restrict__ A2,
    const float* __restrict__ B, const float* __restrict__ bias,
    float* __restrict__ C, int M, int N, int K) {
  __shared__ float As[16][64];
  __shared__ float Bs[16][64];
  int tid = threadIdx.x;
  int n0 = blockIdx.x * 64, m0 = blockIdx.y * 64;
  int tx = tid & 15, ty = tid >> 4;
  int ar = tid >> 2, ac = tid & 3;
  int bkr = tid >> 4, bc = tid & 15;
  float acc[4][4] = {};
  for (int k0 = 0; k0 < K; k0 += 16) {
    float4 av = *(const float4*)(A + (long)(m0 + ar) * K + k0 + ac * 4);
    if (HALF) {
      float4 av2 = *(const float4*)(A2 + (long)(m0 + ar) * K + k0 + ac * 4);
      av.x = 0.5f * (av.x + av2.x); av.y = 0.5f * (av.y + av2.y);
      av.z = 0.5f * (av.z + av2.z); av.w = 0.5f * (av.w + av2.w);
    }
    As[ac * 4 + 0][ar] = av.x; As[ac * 4 + 1][ar] = av.y;
    As[ac * 4 + 2][ar] = av.z; As[ac * 4 + 3][ar] = av.w;
    int bn = n0 + bc * 4;
    float4 bv;
    if (bn + 3 < N) {
      bv = *(const float4*)(B + (long)(k0 + bkr) * N + bn);
    } else {
      float tmp[4];
      #pragma unroll
      for (int jj = 0; jj < 4; ++jj)
        tmp[jj] = (bn + jj < N) ? B[(long)(k0 + bkr) * N + bn + jj] : 0.f;
      bv.x = tmp[0]; bv.y = tmp[1]; bv.z = tmp[2]; bv.w = tmp[3];
    }
    *(float4*)&Bs[bkr][bc * 4] = bv;
    __syncthreads();
    #pragma unroll
    for (int kk = 0; kk < 16; ++kk) {
      float4 a = *(const float4*)&As[kk][ty * 4];
      float4 b = *(const float4*)&Bs[kk][tx * 4];
      acc[0][0] += a.x * b.x; acc[0][1] += a.x * b.y; acc[0][2] += a.x * b.z; acc[0][3] += a.x * b.w;
      acc[1][0] += a.y * b.x; acc[1][1] += a.y * b.y; acc[1][2] += a.y * b.z; acc[1][3] += a.y * b.w;
      acc[2][0] += a.z * b.x; acc[2][1] += a.z * b.y; acc[2][2] += a.z * b.z; acc[2][3] += a.z * b.w;
      acc[3][0] += a.w * b.x; acc[3][1] += a.w * b.y; acc[3][2] += a.w * b.z; acc[3][3] += a.w * b.w;
    }
    __syncthreads();
  }
  #pragma unroll
  for (int i = 0; i < 4; ++i) {
    int m = m0 + ty * 4 + i;
    #pragma unroll
    for (int j = 0; j < 4; ++j) {
      int n = n0 + tx * 4 + j;
      if (n >= N) continue;
      float v = acc[i][j];
      if (BIAS) v += bias[n];
      if (RELU) v = fmaxf(v, 0.f);
      long idx;
      if (MAP == 1) {
        int b = m >> 11, t = m & 2047, hh = n >> 6, dd = n & 63;
        idx = (((long)(b * 8 + hh)) * T_LEN + t) * 64 + dd;
      } else {
        idx = (long)m * N + n;
      }
      if (RES) v += C[idx];
      C[idx] = v;
    }
  }
}

// ---------------------------------------------------------------- f16 MFMA GEMM (FFN, v, wo)
// A: [M][K] f16, Bt: [N][K] f16. MAP1 = per-head scatter (f16 out).
template<int MAP, int BIAS, int GELU, int RES, int BM, int BN, int WM, int WN>
__global__ __launch_bounds__(256) void k_mgemm(
    const ushort* __restrict__ A, const ushort* __restrict__ Bt,
    const float* __restrict__ bias, __half* __restrict__ Ch,
    float* __restrict__ Cf, int M, int N, int K) {
  constexpr int MF = WM / 16, NF = WN / 16;
  constexpr int NWC = BN / WN;
  __shared__ ushort As[BM * 40];
  __shared__ ushort Bs[BN * 40];
  int tid = threadIdx.x;
  int m0 = blockIdx.y * BM, n0 = blockIdx.x * BN;
  int wid = tid >> 6, lane = tid & 63;
  int wr = wid / NWC, wc = wid % NWC;
  int r = lane & 15, kg = lane >> 4;
  f32x4 acc[MF][NF] = {};
  for (int k0 = 0; k0 < K; k0 += 32) {
    __syncthreads();
    for (int idx = tid; idx < BM * 4; idx += 256) {
      int row = idx >> 2, kq = idx & 3;
      *(short8v*)&As[row * 40 + kq * 8] =
          *(const short8v*)(A + (long)(m0 + row) * K + k0 + kq * 8);
    }
    for (int idx = tid; idx < BN * 4; idx += 256) {
      int row = idx >> 2, kq = idx & 3;
      *(short8v*)&Bs[row * 40 + kq * 8] =
          *(const short8v*)(Bt + (long)(n0 + row) * K + k0 + kq * 8);
    }
    __syncthreads();
    half8v af[MF], bf[NF];
    #pragma unroll
    for (int i = 0; i < MF; ++i)
      af[i] = *(const half8v*)&As[(wr * WM + i * 16 + r) * 40 + kg * 8];
    #pragma unroll
    for (int j = 0; j < NF; ++j)
      bf[j] = *(const half8v*)&Bs[(wc * WN + j * 16 + r) * 40 + kg * 8];
    #pragma unroll
    for (int i = 0; i < MF; ++i)
      #pragma unroll
      for (int j = 0; j < NF; ++j)
        acc[i][j] = __builtin_amdgcn_mfma_f32_16x16x32_f16(af[i], bf[j], acc[i][j], 0, 0, 0);
  }
  #pragma unroll
  for (int i = 0; i < MF; ++i) {
    int mb = m0 + wr * WM + i * 16 + kg * 4;
    #pragma unroll
    for (int j = 0; j < NF; ++j) {
      int n = n0 + wc * WN + j * 16 + r;
      float bv = BIAS ? bias[n] : 0.f;
      #pragma unroll
      for (int q = 0; q < 4; ++q) {
        float v = acc[i][j][q] + bv;
        if (GELU) v = 0.5f * v * (1.f + erff(v * 0.70710678118654752f));
        long idx;
        if (MAP == 1) {
          int m = mb + q;
          int b = m >> 11, t = m & 2047, hh = n >> 6, dd = n & 63;
          idx = (((long)(b * 8 + hh)) * T_LEN + t) * 64 + dd;
        } else {
          idx = (long)(mb + q) * N + n;
        }
        if (RES) Cf[idx] += v;
        else Ch[idx] = __float2half(v);
      }
    }
  }
}

// tiled transpose + f32->f16: dst[c][r] = h(src[r][c]); src R x C
__global__ __launch_bounds__(256) void k_tcvt(
    const float* __restrict__ src, __half* __restrict__ dst, int R, int C) {
  __shared__ float tile[32][33];
  int c0 = blockIdx.x * 32, r0 = blockIdx.y * 32;
  int tx = threadIdx.x & 31, ty = threadIdx.x >> 5;
  #pragma unroll
  for (int i = 0; i < 4; ++i)
    tile[ty + i * 8][tx] = src[(long)(r0 + ty + i * 8) * C + c0 + tx];
  __syncthreads();
  #pragma unroll
  for (int i = 0; i < 4; ++i)
    dst[(long)(c0 + ty + i * 8) * R + r0 + tx] = __float2half(tile[tx][ty + i * 8]);
}

// ---------------------------------------------------------------- qk prep: normalized f16 K + f32 row norm
__global__ __launch_bounds__(256) void k_qprep(
    const float* __restrict__ qk, __half* __restrict__ kn, float* __restrict__ qnorm) {
  int row = blockIdx.x * 4 + (threadIdx.x >> 6);
  int d = threadIdx.x & 63;
  float v = qk[(long)row * 64 + d];
  float s2 = v * v;
  #pragma unroll
  for (int off = 1; off < 64; off <<= 1) s2 += __shfl_xor(s2, off);
  float nrm = fmaxf(sqrtf(s2), 1e-12f);
  kn[(long)row * 64 + d] = __float2half(v / nrm);
  if (d == 0) qnorm[row] = nrm;
}

// ---------------------------------------------------------------- LSH hashing (f32)
__global__ __launch_bounds__(256) void k_hash(
    const float* __restrict__ qk, const float* __restrict__ rot,
    int* __restrict__ buckets) {
  int bhid = blockIdx.x >> 6; int t0 = (blockIdx.x & 63) * 32;
  __shared__ float qrow[32][64];
  __shared__ float rl[64][8][20];
  for (int idx = threadIdx.x; idx < 32 * 64; idx += 256) {
    int tok = idx >> 6, f = idx & 63;
    qrow[tok][f] = qk[((long)bhid * T_LEN + t0 + tok) * 64 + f];
  }
  for (int idx = threadIdx.x; idx < 64 * 128; idx += 256) {
    int f = idx >> 7, rem = idx & 127, hh = rem >> 4, ii = rem & 15;
    rl[f][hh][ii] = rot[idx];
  }
  __syncthreads();
  int tok = threadIdx.x >> 3, h = threadIdx.x & 7;
  float acc[16] = {};
  for (int f = 0; f < 64; ++f) {
    float qv = qrow[tok][f];
    #pragma unroll
    for (int i = 0; i < 16; ++i) acc[i] += qv * rl[f][h][i];
  }
  float best = acc[0]; int bi = 0;
  #pragma unroll
  for (int i = 1; i < 16; ++i) if (acc[i] > best) { best = acc[i]; bi = i; }
  #pragma unroll
  for (int i = 0; i < 16; ++i) if (-acc[i] > best) { best = -acc[i]; bi = 16 + i; }
  buckets[((long)bhid * 8 + h) * T_LEN + t0 + tok] = bi;
}

// ---------------------------------------------------------------- stable counting sort
__global__ __launch_bounds__(256) void k_sort(
    const int* __restrict__ buckets, int* __restrict__ st) {
  int bh = blockIdx.x >> 3, h = blockIdx.x & 7;
  const int* bk = buckets + ((long)bh * 8 + h) * T_LEN;
  __shared__ unsigned char lb[2048];
  __shared__ int hist[32], cnt[32];
  __shared__ int whist[4][32];
  if (threadIdx.x < 32) hist[threadIdx.x] = 0;
  __syncthreads();
  for (int p = threadIdx.x; p < 2048; p += 256) {
    int v = bk[p]; lb[p] = (unsigned char)v; atomicAdd(&hist[v], 1);
  }
  __syncthreads();
  if (threadIdx.x == 0) {
    int run = 0;
    for (int i = 0; i < 32; ++i) { cnt[i] = run; run += hist[i]; }
  }
  __syncthreads();
  int lane = threadIdx.x & 63, w = threadIdx.x >> 6;
  unsigned long long mlt = (1ull << lane) - 1ull;
  int* outp = st + (long)bh * (NHASH * T_LEN) + h * T_LEN;
  for (int tile = 0; tile < 8; ++tile) {
    int p = tile * 256 + threadIdx.x;
    int myb = lb[p];
    int wrank = 0;
    for (int bv = 0; bv < 32; ++bv) {
      unsigned long long mm = __ballot(myb == bv);
      if (myb == bv) wrank = __popcll(mm & mlt);
      if (lane == bv) whist[w][bv] = __popcll(mm);
    }
    __syncthreads();
    int off = cnt[myb];
    for (int w2 = 0; w2 < w; ++w2) off += whist[w2][myb];
    outp[off + wrank] = p;
    __syncthreads();
    if (threadIdx.x < 32)
      cnt[threadIdx.x] += whist[0][threadIdx.x] + whist[1][threadIdx.x] +
                          whist[2][threadIdx.x] + whist[3][threadIdx.x];
    __syncthreads();
  }
}

// ---------------------------------------------------------------- MFMA chunked attention
// Per block (256 thr = 4 waves): one (bh, chunk). S^T = Kn·Kn^T scaled per-col by qnorm,
// col-softmax in registers, P -> LDS, O = P·V via V^T tiles. D-frag: col=lane&15, row=kg*4+reg+16*frag.
__global__ __launch_bounds__(256) void k_attn_mfma(
    const ushort* __restrict__ kn, const float* __restrict__ qnorm,
    const ushort* __restrict__ vv, const int* __restrict__ st,
    float* __restrict__ o, float* __restrict__ lg) {
  __shared__ ushort Kb[128 * 72];   // [kv][d] normalized K
  __shared__ ushort Vt[64 * 136];   // [d][kv] V transposed
  __shared__ ushort Ps[64 * 136];   // [q][kv] softmax probs
  __shared__ int   kpos[128];
  __shared__ float qn[64];
  int bh = blockIdx.x >> 8, c = blockIdx.x & 255;
  int h = c >> 5, cp = (c + 255) & 255;
  int tid = threadIdx.x, lane = tid & 63, w = tid >> 6;
  int r16 = lane & 15, kg = lane >> 4;
  const int* stb = st + (long)bh * (NHASH * T_LEN);
  if (tid < 128) kpos[tid] = stb[((tid < 64) ? c : cp) * 64 + (tid & 63)];
  __syncthreads();
  if (tid < 64) qn[tid] = qnorm[bh * T_LEN + kpos[tid]];
  const ushort* knb = kn + (long)bh * T_LEN * 64;
  const ushort* vvb = vv + (long)bh * T_LEN * 64;
  // stage Kn rows (128 x 64)
  for (int idx = tid; idx < 1024; idx += 256) {
    int rr = idx >> 3, p = idx & 7;
    *(short8v*)&Kb[rr * 72 + p * 8] = *(const short8v*)(knb + (long)kpos[rr] * 64 + p * 8);
  }
  // stage V transposed: thread handles rows (rr, rr+1), d-range w*16..w*16+15
  {
    int rr = (tid & 63) * 2;
    ushort a[16], b[16];
    *(short8v*)&a[0] = *(const short8v*)(vvb + (long)kpos[rr] * 64 + w * 16);
    *(short8v*)&a[8] = *(const short8v*)(vvb + (long)kpos[rr] * 64 + w * 16 + 8);
    *(short8v*)&b[0] = *(const short8v*)(vvb + (long)kpos[rr + 1] * 64 + w * 16);
    *(short8v*)&b[8] = *(const short8v*)(vvb + (long)kpos[rr + 1] * 64 + w * 16 + 8);
    #pragma unroll
    for (int i = 0; i < 16; ++i) {
      int d = w * 16 + i;
      *(unsigned int*)&Vt[d * 136 + rr] = (unsigned int)a[i] | ((unsigned int)b[i] << 16);
    }
  }
  __syncthreads();
  // S^T: D[kv][q], wave w owns q-cols w*16..w*16+15
  f32x4 sacc[8] = {};
  #pragma unroll
  for (int ks = 0; ks < 2; ++ks) {
    half8v bfq = *(const half8v*)&Kb[(w * 16 + r16) * 72 + ks * 32 + kg * 8];
    #pragma unroll
    for (int i = 0; i < 8; ++i) {
      half8v af = *(const half8v*)&Kb[(i * 16 + r16) * 72 + ks * 32 + kg * 8];
      sacc[i] = __builtin_amdgcn_mfma_f32_16x16x32_f16(af, bfq, sacc[i], 0, 0, 0);
    }
  }
  // mask + col softmax (q = w*16+r16; per lane 32 kv values)
  int q = w * 16 + r16;
  int qposv = kpos[q];
  float sc = 0.125f * qn[q];
  float vals[8][4];
  float mx = -3.4e38f;
  #pragma unroll
  for (int f = 0; f < 8; ++f)
    #pragma unroll
    for (int e = 0; e < 4; ++e) {
      int kv = f * 16 + kg * 4 + e;
      float v = sacc[f][e] * sc;
      if (kpos[kv] == qposv) v = SELF_VAL;
      vals[f][e] = v;
      mx = fmaxf(mx, v);
    }
  mx = fmaxf(mx, __shfl_xor(mx, 16));
  mx = fmaxf(mx, __shfl_xor(mx, 32));
  float sm = 0.f;
  #pragma unroll
  for (int f = 0; f < 8; ++f)
    #pragma unroll
    for (int e = 0; e < 4; ++e) { vals[f][e] = __expf(vals[f][e] - mx); sm += vals[f][e]; }
  sm += __shfl_xor(sm, 16);
  sm += __shfl_xor(sm, 32);
  float inv = 1.f / sm;
  #pragma unroll
  for (int f = 0; f < 8; ++f) {
    ushort4v pw;
    #pragma unroll
    for (int e = 0; e < 4; ++e) pw[e] = __half_as_ushort(__float2half(vals[f][e] * inv));
    *(ushort4v*)&Ps[q * 136 + f * 16 + kg * 4] = pw;
  }
  if (kg == 0) lg[((long)bh * 8 + h) * T_LEN + qposv] = mx + logf(sm);
  __syncthreads();
  // O = P·V : D[q][d], wave w owns d-cols w*16..w*16+15
  f32x4 oacc[4] = {};
  #pragma unroll
  for (int ks = 0; ks < 4; ++ks) {
    half8v vf = *(const half8v*)&Vt[(w * 16 + r16) * 136 + ks * 32 + kg * 8];
    #pragma unroll
    for (int i = 0; i < 4; ++i) {
      half8v pf = *(const half8v*)&Ps[(i * 16 + r16) * 136 + ks * 32 + kg * 8];
      oacc[i] = __builtin_amdgcn_mfma_f32_16x16x32_f16(pf, vf, oacc[i], 0, 0, 0);
    }
  }
  long ob = ((long)bh * 8 + h) * T_LEN;
  int d = w * 16 + r16;
  #pragma unroll
  for (int i = 0; i < 4; ++i)
    #pragma unroll
    for (int e = 0; e < 4; ++e)
      o[(ob + kpos[i * 16 + kg * 4 + e]) * 64 + d] = oacc[i][e];
}

// ---------------------------------------------------------------- combine hash rounds (f16 out)
__global__ __launch_bounds__(256) void k_combine(
    const float* __restrict__ o, const float* __restrict__ lg, __half* __restrict__ att) {
  int m = blockIdx.x; int b = m >> 11, t = m & 2047;
  int head = threadIdx.x >> 5, d0 = (threadIdx.x & 31) * 2;
  int bh = b * 8 + head;
  const float* lgp = lg + (long)bh * 8 * T_LEN + t;
  float l[8], mx = -3.4e38f;
  #pragma unroll
  for (int hh = 0; hh < 8; ++hh) { l[hh] = lgp[(long)hh * T_LEN]; mx = fmaxf(mx, l[hh]); }
  float sm = 0.f;
  #pragma unroll
  for (int hh = 0; hh < 8; ++hh) { l[hh] = expf(l[hh] - mx); sm += l[hh]; }
  float inv = 1.f / sm;
  float a0 = 0.f, a1 = 0.f;
  #pragma unroll
  for (int hh = 0; hh < 8; ++hh) {
    const float* op = o + (((long)bh * 8 + hh) * T_LEN + t) * 64 + d0;
    float w_ = l[hh] * inv;
    a0 += w_ * op[0]; a1 += w_ * op[1];
  }
  unsigned int u = (unsigned int)__half_as_ushort(__float2half(a0)) |
                   ((unsigned int)__half_as_ushort(__float2half(a1)) << 16);
  *(unsigned int*)&att[(long)m * 512 + head * 64 + d0] = u;
}

// ---------------------------------------------------------------- host
extern "C" void kernel_launch(void* const* d_in, const int* in_sizes, int n_in,
                              void* d_out, int out_size, void* d_ws, size_t ws_size,
                              hipStream_t stream) {
  const float* spec   = (const float*)d_in[0];
  const float* conv_w = (const float*)d_in[1];
  const float* conv_b = (const float*)d_in[2];
  const float* pe_row = (const float*)d_in[3];
  const float* pe_col = (const float*)d_in[4];
  const float* lnA_g  = (const float*)d_in[5];
  const float* lnA_b  = (const float*)d_in[6];
  const float* wqk    = (const float*)d_in[7];
  const float* wv     = (const float*)d_in[8];
  const float* wo     = (const float*)d_in[9];
  const float* bo     = (const float*)d_in[10];
  const float* lnF_g  = (const float*)d_in[11];
  const float* lnF_b  = (const float*)d_in[12];
  const float* w1     = (const float*)d_in[13];
  const float* b1     = (const float*)d_in[14];
  const float* w2     = (const float*)d_in[15];
  const float* b2     = (const float*)d_in[16];
  const float* lin_w  = (const float*)d_in[17];
  const float* lin_b  = (const float*)d_in[18];
  const float* rot    = (const float*)d_in[19];

  float* ws = (float*)d_ws;
  const long TOKF = (long)NTOK * 512;            // 2,097,152
  float* x1   = ws;                               // TOKF
  float* x2   = x1 + TOKF;                        // TOKF
  float* xn   = x2 + TOKF;                        // TOKF (f32 LN out for qk gemm)
  float* qkb  = xn + TOKF;                        // TOKF (f32 qk, head-scattered)
  float* o    = qkb + TOKF;                       // 16*8*2048*64 = 16.78M
  float* lg   = o + (long)16 * 8 * T_LEN * 64;    // 262144
  int*   stx  = (int*)(lg + (long)16 * 8 * T_LEN);       // 262144 ints
  int*   buckets = stx + (long)16 * NHASH * T_LEN;       // 262144 ints
  float* base = (float*)(buckets + (long)16 * NHASH * T_LEN);
  __half* xnh  = (__half*)base;                   // TOKF halves -> TOKF/2 floats
  __half* att16 = (__half*)(base + TOKF / 2);     // TOKF halves
  __half* vb16  = (__half*)(base + 2 * (TOKF / 2)); // TOKF halves (head-scattered V)
  __half* kn16  = (__half*)(base + 3 * (TOKF / 2)); // TOKF halves (normalized K)
  float* qnorm  = base + 4 * (TOKF / 2);          // 32768
  float* h1region = qnorm + 32768;                // 4.19M floats (h1h halves / colbuf alias)
  __half* h1h   = (__half*)h1region;
  float* colbuf = h1region;                       // alias (conv first)
  float* wreg   = h1region + (long)NTOK * 1024;   // weight region
  __half* w1h   = (__half*)wreg;                  // 512*2048 halves = 0.524M floats
  __half* w2h   = (__half*)(wreg + 524288);       // 0.524M floats
  __half* wvh   = (__half*)(wreg + 2 * 524288);   // 512*512 halves = 0.131M floats
  __half* woh   = (__half*)(wreg + 2 * 524288 + 131072);
  float* Bc     = wreg;                           // alias (conv first), 352256 floats

  dim3 g512(8, 64);
  dim3 glin(2, 64);

  // conv frontend as GEMM
  k_im2col<<<NTOK, 256, 0, stream>>>(spec, colbuf);
  k_wconv<<<688, 256, 0, stream>>>(conv_w, Bc);
  k_gemm<0,0,1,1,0><<<g512, 256, 0, stream>>>(colbuf, nullptr, Bc, conv_b, x1, NTOK, 512, 688);
  k_pe<<<NTOK, 256, 0, stream>>>(pe_row, pe_col, x1, x2);

  for (int l = 0; l < 8; ++l) {
    const long W2 = (long)l * 512 * 512;
    k_ln<2><<<NTOK, 256, 0, stream>>>(x2, lnA_g + l * 512, lnA_b + l * 512, xn, xnh);
    // qk projection stays f32 (feeds hashing)
    k_gemm<1,0,0,0,0><<<g512, 256, 0, stream>>>(xn, nullptr, wqk + W2, nullptr, qkb, NTOK, 512, 512);
    // v projection via f16 MFMA, scattered per head
    k_tcvt<<<dim3(16, 16), 256, 0, stream>>>(wv + W2, wvh, 512, 512);
    k_mgemm<1,0,0,0,128,128,64,64><<<dim3(4, 32), 256, 0, stream>>>(
        (const ushort*)xnh, (const ushort*)wvh, nullptr, vb16, nullptr, NTOK, 512, 512);
    k_qprep<<<8192, 256, 0, stream>>>(qkb, kn16, qnorm);
    k_hash<<<1024, 256, 0, stream>>>(qkb, rot + (long)l * 8192, buckets);
    k_sort<<<128, 256, 0, stream>>>(buckets, stx);
    k_attn_mfma<<<4096, 256, 0, stream>>>((const ushort*)kn16, qnorm, (const ushort*)vb16,
                                          stx, o, lg);
    k_combine<<<NTOK, 256, 0, stream>>>(o, lg, att16);
    // wo projection via f16 MFMA, residual into x1
    k_tcvt<<<dim3(16, 16), 256, 0, stream>>>(wo + W2, woh, 512, 512);
    k_mgemm<0,1,0,1,64,128,32,64><<<dim3(4, 64), 256, 0, stream>>>(
        (const ushort*)att16, (const ushort*)woh, bo + l * 512, nullptr, x1, NTOK, 512, 512);
    // FFN via f16 MFMA
    k_ln<1><<<NTOK, 256, 0, stream>>>(x1, lnF_g + l * 512, lnF_b + l * 512, nullptr, xnh);
    k_tcvt<<<dim3(64, 16), 256, 0, stream>>>(w1 + (long)l * 512 * 2048, w1h, 512, 2048);
    k_mgemm<0,1,1,0,128,128,64,64><<<dim3(16, 32), 256, 0, stream>>>(
        (const ushort*)xnh, (const ushort*)w1h, b1 + (long)l * 2048, h1h, nullptr, NTOK, 2048, 512);
    k_tcvt<<<dim3(16, 64), 256, 0, stream>>>(w2 + (long)l * 2048 * 512, w2h, 2048, 512);
    k_mgemm<0,1,0,1,64,128,32,64><<<dim3(4, 64), 256, 0, stream>>>(
        (const ushort*)h1h, (const ushort*)w2h, b2 + (long)l * 512, nullptr, x2, NTOK, 512, 2048);
  }
  k_gemm<0,0,1,0,1><<<glin, 256, 0, stream>>>(x1, x2, lin_w, lin_b, (float*)d_out, NTOK, 88, 512);
}

// Round 5
// 2199.388 us; speedup vs baseline: 3.8063x; 1.2390x over previous
//
#include <hip/hip_runtime.h>
#include <hip/hip_fp16.h>
#include <cstdint>

#define T_LEN 2048
#define NTOK  4096      // B*T
#define NHASH 8
#define SELF_VAL -5e4f

typedef __attribute__((ext_vector_type(8))) short short8v;
typedef __attribute__((ext_vector_type(8))) _Float16 half8v;
typedef __attribute__((ext_vector_type(4))) float f32x4;
typedef __attribute__((ext_vector_type(4))) unsigned short ushort4v;

// ---------------------------------------------------------------- im2col (conv k=3 pad=1), K padded to 688
__global__ __launch_bounds__(256) void k_im2col(
    const float* __restrict__ spec, float* __restrict__ col) {
  int m = blockIdx.x; int b = m >> 11, t = m & 2047;
  for (int c = threadIdx.x; c < 688; c += 256) {
    float v = 0.f;
    if (c < 687) {
      int k = (c >= 458) ? 2 : (c >= 229 ? 1 : 0);
      int i = c - k * 229;
      int tt = t + k - 1;
      if (tt >= 0 && tt < T_LEN) v = spec[((long)b * T_LEN + tt) * 229 + i];
    }
    col[(long)m * 688 + c] = v;
  }
}

__global__ __launch_bounds__(256) void k_wconv(
    const float* __restrict__ w, float* __restrict__ Bc) {
  int c = blockIdx.x;
  int k = (c >= 458) ? 2 : (c >= 229 ? 1 : 0);
  int i = c - k * 229;
  for (int o = threadIdx.x; o < 512; o += 256) {
    float v = (c < 687) ? w[((long)o * 229 + i) * 3 + k] : 0.f;
    Bc[(long)c * 512 + o] = v;
  }
}

__global__ __launch_bounds__(256) void k_pe(
    const float* __restrict__ pe_row, const float* __restrict__ pe_col,
    float* __restrict__ x1, float* __restrict__ x2) {
  int m = blockIdx.x, t = m & 2047;
  for (int o = threadIdx.x; o < 512; o += 256) {
    long idx = (long)m * 512 + o;
    float v = x1[idx] + ((o < 256) ? pe_row[(t >> 6) * 256 + o]
                                   : pe_col[(t & 63) * 256 + (o - 256)]);
    x1[idx] = v; x2[idx] = v;
  }
}

// ---------------------------------------------------------------- layernorm; OUTB: 0=f32, 1=f16, 2=both
template<int OUTB>
__global__ __launch_bounds__(256) void k_ln(
    const float* __restrict__ x, const float* __restrict__ g,
    const float* __restrict__ bb, float* __restrict__ out,
    __half* __restrict__ outh) {
  int row = blockIdx.x, tid = threadIdx.x;
  const float* xr = x + (long)row * 512;
  float v0 = xr[tid], v1 = xr[tid + 256];
  float s1 = v0 + v1, s2 = v0 * v0 + v1 * v1;
  #pragma unroll
  for (int off = 1; off < 64; off <<= 1) { s1 += __shfl_xor(s1, off); s2 += __shfl_xor(s2, off); }
  __shared__ float r1[4], r2[4];
  int w = tid >> 6, lane = tid & 63;
  if (lane == 0) { r1[w] = s1; r2[w] = s2; }
  __syncthreads();
  float S1 = r1[0] + r1[1] + r1[2] + r1[3];
  float S2 = r2[0] + r2[1] + r2[2] + r2[3];
  float mean = S1 * (1.f / 512.f);
  float var  = S2 * (1.f / 512.f) - mean * mean;
  float rstd = 1.f / sqrtf(var + 1e-5f);
  float o0 = (v0 - mean) * rstd * g[tid] + bb[tid];
  float o1 = (v1 - mean) * rstd * g[tid + 256] + bb[tid + 256];
  if (OUTB != 1) {
    out[(long)row * 512 + tid]       = o0;
    out[(long)row * 512 + tid + 256] = o1;
  }
  if (OUTB >= 1) {
    outh[(long)row * 512 + tid]       = __float2half(o0);
    outh[(long)row * 512 + tid + 256] = __float2half(o1);
  }
}

// ---------------------------------------------------------------- f32 SGEMM (qk/conv/lin)
template<int MAP, int RES, int BIAS, int RELU, int HALF>
__global__ __launch_bounds__(256) void k_gemm(
    const float* __restrict__ A, const float* __restrict__ A2,
    const float* __restrict__ B, const float* __restrict__ bias,
    float* __restrict__ C, int M, int N, int K) {
  __shared__ float As[16][64];
  __shared__ float Bs[16][64];
  int tid = threadIdx.x;
  int n0 = blockIdx.x * 64, m0 = blockIdx.y * 64;
  int tx = tid & 15, ty = tid >> 4;
  int ar = tid >> 2, ac = tid & 3;
  int bkr = tid >> 4, bc = tid & 15;
  float acc[4][4] = {};
  for (int k0 = 0; k0 < K; k0 += 16) {
    float4 av = *(const float4*)(A + (long)(m0 + ar) * K + k0 + ac * 4);
    if (HALF) {
      float4 av2 = *(const float4*)(A2 + (long)(m0 + ar) * K + k0 + ac * 4);
      av.x = 0.5f * (av.x + av2.x); av.y = 0.5f * (av.y + av2.y);
      av.z = 0.5f * (av.z + av2.z); av.w = 0.5f * (av.w + av2.w);
    }
    As[ac * 4 + 0][ar] = av.x; As[ac * 4 + 1][ar] = av.y;
    As[ac * 4 + 2][ar] = av.z; As[ac * 4 + 3][ar] = av.w;
    int bn = n0 + bc * 4;
    float4 bv;
    if (bn + 3 < N) {
      bv = *(const float4*)(B + (long)(k0 + bkr) * N + bn);
    } else {
      float tmp[4];
      #pragma unroll
      for (int jj = 0; jj < 4; ++jj)
        tmp[jj] = (bn + jj < N) ? B[(long)(k0 + bkr) * N + bn + jj] : 0.f;
      bv.x = tmp[0]; bv.y = tmp[1]; bv.z = tmp[2]; bv.w = tmp[3];
    }
    *(float4*)&Bs[bkr][bc * 4] = bv;
    __syncthreads();
    #pragma unroll
    for (int kk = 0; kk < 16; ++kk) {
      float4 a = *(const float4*)&As[kk][ty * 4];
      float4 b = *(const float4*)&Bs[kk][tx * 4];
      acc[0][0] += a.x * b.x; acc[0][1] += a.x * b.y; acc[0][2] += a.x * b.z; acc[0][3] += a.x * b.w;
      acc[1][0] += a.y * b.x; acc[1][1] += a.y * b.y; acc[1][2] += a.y * b.z; acc[1][3] += a.y * b.w;
      acc[2][0] += a.z * b.x; acc[2][1] += a.z * b.y; acc[2][2] += a.z * b.z; acc[2][3] += a.z * b.w;
      acc[3][0] += a.w * b.x; acc[3][1] += a.w * b.y; acc[3][2] += a.w * b.z; acc[3][3] += a.w * b.w;
    }
    __syncthreads();
  }
  #pragma unroll
  for (int i = 0; i < 4; ++i) {
    int m = m0 + ty * 4 + i;
    #pragma unroll
    for (int j = 0; j < 4; ++j) {
      int n = n0 + tx * 4 + j;
      if (n >= N) continue;
      float v = acc[i][j];
      if (BIAS) v += bias[n];
      if (RELU) v = fmaxf(v, 0.f);
      long idx;
      if (MAP == 1) {
        int b = m >> 11, t = m & 2047, hh = n >> 6, dd = n & 63;
        idx = (((long)(b * 8 + hh)) * T_LEN + t) * 64 + dd;
      } else {
        idx = (long)m * N + n;
      }
      if (RES) v += C[idx];
      C[idx] = v;
    }
  }
}

// ---------------------------------------------------------------- f16 MFMA GEMM, 64x64 tile, 1D grid + XCD swizzle
// A: [M][K] f16, Bt: [N][K] f16. MAP1 = per-head scatter (f16 out).
template<int MAP, int BIAS, int GELU, int RES>
__global__ __launch_bounds__(256) void k_mgemm(
    const ushort* __restrict__ A, const ushort* __restrict__ Bt,
    const float* __restrict__ bias, __half* __restrict__ Ch,
    float* __restrict__ Cf, int M, int N, int K, int ncol) {
  constexpr int BM = 64, BN = 64, WM = 32, WN = 32;
  constexpr int MF = WM / 16, NF = WN / 16;   // 2 x 2
  __shared__ ushort As[BM * 40];
  __shared__ ushort Bs[BN * 40];
  int tid = threadIdx.x;
  // bijective XCD swizzle (nwg % 8 == 0 guaranteed by launch)
  int nwg = gridDim.x;
  int q8 = nwg >> 3;
  int wg = blockIdx.x;
  int swz = (wg & 7) * q8 + (wg >> 3);
  int m0 = (swz / ncol) * BM, n0 = (swz % ncol) * BN;
  int wid = tid >> 6, lane = tid & 63;
  int wr = wid >> 1, wc = wid & 1;
  int r = lane & 15, kg = lane >> 4;
  int ar = tid >> 2, ac = tid & 3;    // 64 rows x 4 k-quads staging
  f32x4 acc[MF][NF] = {};
  for (int k0 = 0; k0 < K; k0 += 32) {
    __syncthreads();
    *(short8v*)&As[ar * 40 + ac * 8] =
        *(const short8v*)(A + (long)(m0 + ar) * K + k0 + ac * 8);
    *(short8v*)&Bs[ar * 40 + ac * 8] =
        *(const short8v*)(Bt + (long)(n0 + ar) * K + k0 + ac * 8);
    __syncthreads();
    half8v af[MF], bf[NF];
    #pragma unroll
    for (int i = 0; i < MF; ++i)
      af[i] = *(const half8v*)&As[(wr * WM + i * 16 + r) * 40 + kg * 8];
    #pragma unroll
    for (int j = 0; j < NF; ++j)
      bf[j] = *(const half8v*)&Bs[(wc * WN + j * 16 + r) * 40 + kg * 8];
    #pragma unroll
    for (int i = 0; i < MF; ++i)
      #pragma unroll
      for (int j = 0; j < NF; ++j)
        acc[i][j] = __builtin_amdgcn_mfma_f32_16x16x32_f16(af[i], bf[j], acc[i][j], 0, 0, 0);
  }
  #pragma unroll
  for (int i = 0; i < MF; ++i) {
    int mb = m0 + wr * WM + i * 16 + kg * 4;
    #pragma unroll
    for (int j = 0; j < NF; ++j) {
      int n = n0 + wc * WN + j * 16 + r;
      float bv = BIAS ? bias[n] : 0.f;
      #pragma unroll
      for (int q = 0; q < 4; ++q) {
        float v = acc[i][j][q] + bv;
        if (GELU) v = 0.5f * v * (1.f + erff(v * 0.70710678118654752f));
        long idx;
        if (MAP == 1) {
          int m = mb + q;
          int b = m >> 11, t = m & 2047, hh = n >> 6, dd = n & 63;
          idx = (((long)(b * 8 + hh)) * T_LEN + t) * 64 + dd;
        } else {
          idx = (long)(mb + q) * N + n;
        }
        if (RES) Cf[idx] += v;
        else Ch[idx] = __float2half(v);
      }
    }
  }
}

// tiled transpose + f32->f16: dst[c][r] = h(src[r][c]); src R x C
__global__ __launch_bounds__(256) void k_tcvt(
    const float* __restrict__ src, __half* __restrict__ dst, int R, int C) {
  __shared__ float tile[32][33];
  int c0 = blockIdx.x * 32, r0 = blockIdx.y * 32;
  int tx = threadIdx.x & 31, ty = threadIdx.x >> 5;
  #pragma unroll
  for (int i = 0; i < 4; ++i)
    tile[ty + i * 8][tx] = src[(long)(r0 + ty + i * 8) * C + c0 + tx];
  __syncthreads();
  #pragma unroll
  for (int i = 0; i < 4; ++i)
    dst[(long)(c0 + ty + i * 8) * R + r0 + tx] = __float2half(tile[tx][ty + i * 8]);
}

// ---------------------------------------------------------------- qk prep: normalized f16 K + f32 row norm
__global__ __launch_bounds__(256) void k_qprep(
    const float* __restrict__ qk, __half* __restrict__ kn, float* __restrict__ qnorm) {
  int row = blockIdx.x * 4 + (threadIdx.x >> 6);
  int d = threadIdx.x & 63;
  float v = qk[(long)row * 64 + d];
  float s2 = v * v;
  #pragma unroll
  for (int off = 1; off < 64; off <<= 1) s2 += __shfl_xor(s2, off);
  float nrm = fmaxf(sqrtf(s2), 1e-12f);
  kn[(long)row * 64 + d] = __float2half(v / nrm);
  if (d == 0) qnorm[row] = nrm;
}

// ---------------------------------------------------------------- LSH hashing (f32)
__global__ __launch_bounds__(256) void k_hash(
    const float* __restrict__ qk, const float* __restrict__ rot,
    int* __restrict__ buckets) {
  int bhid = blockIdx.x >> 6; int t0 = (blockIdx.x & 63) * 32;
  __shared__ float qrow[32][64];
  __shared__ float rl[64][8][20];
  for (int idx = threadIdx.x; idx < 32 * 64; idx += 256) {
    int tok = idx >> 6, f = idx & 63;
    qrow[tok][f] = qk[((long)bhid * T_LEN + t0 + tok) * 64 + f];
  }
  for (int idx = threadIdx.x; idx < 64 * 128; idx += 256) {
    int f = idx >> 7, rem = idx & 127, hh = rem >> 4, ii = rem & 15;
    rl[f][hh][ii] = rot[idx];
  }
  __syncthreads();
  int tok = threadIdx.x >> 3, h = threadIdx.x & 7;
  float acc[16] = {};
  for (int f = 0; f < 64; ++f) {
    float qv = qrow[tok][f];
    #pragma unroll
    for (int i = 0; i < 16; ++i) acc[i] += qv * rl[f][h][i];
  }
  float best = acc[0]; int bi = 0;
  #pragma unroll
  for (int i = 1; i < 16; ++i) if (acc[i] > best) { best = acc[i]; bi = i; }
  #pragma unroll
  for (int i = 0; i < 16; ++i) if (-acc[i] > best) { best = -acc[i]; bi = 16 + i; }
  buckets[((long)bhid * 8 + h) * T_LEN + t0 + tok] = bi;
}

// ---------------------------------------------------------------- stable counting sort
__global__ __launch_bounds__(256) void k_sort(
    const int* __restrict__ buckets, int* __restrict__ st) {
  int bh = blockIdx.x >> 3, h = blockIdx.x & 7;
  const int* bk = buckets + ((long)bh * 8 + h) * T_LEN;
  __shared__ unsigned char lb[2048];
  __shared__ int hist[32], cnt[32];
  __shared__ int whist[4][32];
  if (threadIdx.x < 32) hist[threadIdx.x] = 0;
  __syncthreads();
  for (int p = threadIdx.x; p < 2048; p += 256) {
    int v = bk[p]; lb[p] = (unsigned char)v; atomicAdd(&hist[v], 1);
  }
  __syncthreads();
  if (threadIdx.x == 0) {
    int run = 0;
    for (int i = 0; i < 32; ++i) { cnt[i] = run; run += hist[i]; }
  }
  __syncthreads();
  int lane = threadIdx.x & 63, w = threadIdx.x >> 6;
  unsigned long long mlt = (1ull << lane) - 1ull;
  int* outp = st + (long)bh * (NHASH * T_LEN) + h * T_LEN;
  for (int tile = 0; tile < 8; ++tile) {
    int p = tile * 256 + threadIdx.x;
    int myb = lb[p];
    int wrank = 0;
    for (int bv = 0; bv < 32; ++bv) {
      unsigned long long mm = __ballot(myb == bv);
      if (myb == bv) wrank = __popcll(mm & mlt);
      if (lane == bv) whist[w][bv] = __popcll(mm);
    }
    __syncthreads();
    int off = cnt[myb];
    for (int w2 = 0; w2 < w; ++w2) off += whist[w2][myb];
    outp[off + wrank] = p;
    __syncthreads();
    if (threadIdx.x < 32)
      cnt[threadIdx.x] += whist[0][threadIdx.x] + whist[1][threadIdx.x] +
                          whist[2][threadIdx.x] + whist[3][threadIdx.x];
    __syncthreads();
  }
}

// ---------------------------------------------------------------- MFMA chunked attention (o out f16)
__global__ __launch_bounds__(256) void k_attn_mfma(
    const ushort* __restrict__ kn, const float* __restrict__ qnorm,
    const ushort* __restrict__ vv, const int* __restrict__ st,
    __half* __restrict__ o, float* __restrict__ lg) {
  __shared__ ushort Kb[128 * 72];   // [kv][d] normalized K
  __shared__ ushort Vt[64 * 136];   // [d][kv] V transposed
  __shared__ ushort Ps[64 * 136];   // [q][kv] softmax probs
  __shared__ int   kpos[128];
  __shared__ float qn[64];
  int bh = blockIdx.x >> 8, c = blockIdx.x & 255;
  int h = c >> 5, cp = (c + 255) & 255;
  int tid = threadIdx.x, lane = tid & 63, w = tid >> 6;
  int r16 = lane & 15, kg = lane >> 4;
  const int* stb = st + (long)bh * (NHASH * T_LEN);
  if (tid < 128) kpos[tid] = stb[((tid < 64) ? c : cp) * 64 + (tid & 63)];
  __syncthreads();
  if (tid < 64) qn[tid] = qnorm[bh * T_LEN + kpos[tid]];
  const ushort* knb = kn + (long)bh * T_LEN * 64;
  const ushort* vvb = vv + (long)bh * T_LEN * 64;
  for (int idx = tid; idx < 1024; idx += 256) {
    int rr = idx >> 3, p = idx & 7;
    *(short8v*)&Kb[rr * 72 + p * 8] = *(const short8v*)(knb + (long)kpos[rr] * 64 + p * 8);
  }
  {
    int rr = (tid & 63) * 2;
    ushort a[16], b[16];
    *(short8v*)&a[0] = *(const short8v*)(vvb + (long)kpos[rr] * 64 + w * 16);
    *(short8v*)&a[8] = *(const short8v*)(vvb + (long)kpos[rr] * 64 + w * 16 + 8);
    *(short8v*)&b[0] = *(const short8v*)(vvb + (long)kpos[rr + 1] * 64 + w * 16);
    *(short8v*)&b[8] = *(const short8v*)(vvb + (long)kpos[rr + 1] * 64 + w * 16 + 8);
    #pragma unroll
    for (int i = 0; i < 16; ++i) {
      int d = w * 16 + i;
      *(unsigned int*)&Vt[d * 136 + rr] = (unsigned int)a[i] | ((unsigned int)b[i] << 16);
    }
  }
  __syncthreads();
  f32x4 sacc[8] = {};
  #pragma unroll
  for (int ks = 0; ks < 2; ++ks) {
    half8v bfq = *(const half8v*)&Kb[(w * 16 + r16) * 72 + ks * 32 + kg * 8];
    #pragma unroll
    for (int i = 0; i < 8; ++i) {
      half8v af = *(const half8v*)&Kb[(i * 16 + r16) * 72 + ks * 32 + kg * 8];
      sacc[i] = __builtin_amdgcn_mfma_f32_16x16x32_f16(af, bfq, sacc[i], 0, 0, 0);
    }
  }
  int q = w * 16 + r16;
  int qposv = kpos[q];
  float sc = 0.125f * qn[q];
  float vals[8][4];
  float mx = -3.4e38f;
  #pragma unroll
  for (int f = 0; f < 8; ++f)
    #pragma unroll
    for (int e = 0; e < 4; ++e) {
      int kv = f * 16 + kg * 4 + e;
      float v = sacc[f][e] * sc;
      if (kpos[kv] == qposv) v = SELF_VAL;
      vals[f][e] = v;
      mx = fmaxf(mx, v);
    }
  mx = fmaxf(mx, __shfl_xor(mx, 16));
  mx = fmaxf(mx, __shfl_xor(mx, 32));
  float sm = 0.f;
  #pragma unroll
  for (int f = 0; f < 8; ++f)
    #pragma unroll
    for (int e = 0; e < 4; ++e) { vals[f][e] = __expf(vals[f][e] - mx); sm += vals[f][e]; }
  sm += __shfl_xor(sm, 16);
  sm += __shfl_xor(sm, 32);
  float inv = 1.f / sm;
  #pragma unroll
  for (int f = 0; f < 8; ++f) {
    ushort4v pw;
    #pragma unroll
    for (int e = 0; e < 4; ++e) pw[e] = __half_as_ushort(__float2half(vals[f][e] * inv));
    *(ushort4v*)&Ps[q * 136 + f * 16 + kg * 4] = pw;
  }
  if (kg == 0) lg[((long)bh * 8 + h) * T_LEN + qposv] = mx + logf(sm);
  __syncthreads();
  f32x4 oacc[4] = {};
  #pragma unroll
  for (int ks = 0; ks < 4; ++ks) {
    half8v vf = *(const half8v*)&Vt[(w * 16 + r16) * 136 + ks * 32 + kg * 8];
    #pragma unroll
    for (int i = 0; i < 4; ++i) {
      half8v pf = *(const half8v*)&Ps[(i * 16 + r16) * 136 + ks * 32 + kg * 8];
      oacc[i] = __builtin_amdgcn_mfma_f32_16x16x32_f16(pf, vf, oacc[i], 0, 0, 0);
    }
  }
  long ob = ((long)bh * 8 + h) * T_LEN;
  int d = w * 16 + r16;
  #pragma unroll
  for (int i = 0; i < 4; ++i)
    #pragma unroll
    for (int e = 0; e < 4; ++e)
      o[(ob + kpos[i * 16 + kg * 4 + e]) * 64 + d] = __float2half(oacc[i][e]);
}

// ---------------------------------------------------------------- combine hash rounds (f16 in/out)
__global__ __launch_bounds__(256) void k_combine(
    const __half* __restrict__ o, const float* __restrict__ lg, __half* __restrict__ att) {
  int m = blockIdx.x; int b = m >> 11, t = m & 2047;
  int head = threadIdx.x >> 5, d0 = (threadIdx.x & 31) * 2;
  int bh = b * 8 + head;
  const float* lgp = lg + (long)bh * 8 * T_LEN + t;
  float l[8], mx = -3.4e38f;
  #pragma unroll
  for (int hh = 0; hh < 8; ++hh) { l[hh] = lgp[(long)hh * T_LEN]; mx = fmaxf(mx, l[hh]); }
  float sm = 0.f;
  #pragma unroll
  for (int hh = 0; hh < 8; ++hh) { l[hh] = expf(l[hh] - mx); sm += l[hh]; }
  float inv = 1.f / sm;
  float a0 = 0.f, a1 = 0.f;
  #pragma unroll
  for (int hh = 0; hh < 8; ++hh) {
    const __half* op = o + (((long)bh * 8 + hh) * T_LEN + t) * 64 + d0;
    float w_ = l[hh] * inv;
    a0 += w_ * __half2float(op[0]); a1 += w_ * __half2float(op[1]);
  }
  unsigned int u = (unsigned int)__half_as_ushort(__float2half(a0)) |
                   ((unsigned int)__half_as_ushort(__float2half(a1)) << 16);
  *(unsigned int*)&att[(long)m * 512 + head * 64 + d0] = u;
}

// ---------------------------------------------------------------- host
extern "C" void kernel_launch(void* const* d_in, const int* in_sizes, int n_in,
                              void* d_out, int out_size, void* d_ws, size_t ws_size,
                              hipStream_t stream) {
  const float* spec   = (const float*)d_in[0];
  const float* conv_w = (const float*)d_in[1];
  const float* conv_b = (const float*)d_in[2];
  const float* pe_row = (const float*)d_in[3];
  const float* pe_col = (const float*)d_in[4];
  const float* lnA_g  = (const float*)d_in[5];
  const float* lnA_b  = (const float*)d_in[6];
  const float* wqk    = (const float*)d_in[7];
  const float* wv     = (const float*)d_in[8];
  const float* wo     = (const float*)d_in[9];
  const float* bo     = (const float*)d_in[10];
  const float* lnF_g  = (const float*)d_in[11];
  const float* lnF_b  = (const float*)d_in[12];
  const float* w1     = (const float*)d_in[13];
  const float* b1     = (const float*)d_in[14];
  const float* w2     = (const float*)d_in[15];
  const float* b2     = (const float*)d_in[16];
  const float* lin_w  = (const float*)d_in[17];
  const float* lin_b  = (const float*)d_in[18];
  const float* rot    = (const float*)d_in[19];

  float* ws = (float*)d_ws;
  const long TOKF = (long)NTOK * 512;            // 2,097,152
  float* x1   = ws;
  float* x2   = x1 + TOKF;
  float* xn   = x2 + TOKF;
  float* qkb  = xn + TOKF;
  __half* o16 = (__half*)(qkb + TOKF);            // 16*8*2048*64 halves
  float* lg   = (float*)(o16 + (long)16 * 8 * T_LEN * 64);
  int*   stx  = (int*)(lg + (long)16 * 8 * T_LEN);
  int*   buckets = stx + (long)16 * NHASH * T_LEN;
  float* base = (float*)(buckets + (long)16 * NHASH * T_LEN);
  __half* xnh  = (__half*)base;
  __half* att16 = (__half*)(base + TOKF / 2);
  __half* vb16  = (__half*)(base + 2 * (TOKF / 2));
  __half* kn16  = (__half*)(base + 3 * (TOKF / 2));
  float* qnorm  = base + 4 * (TOKF / 2);
  float* h1region = qnorm + 32768;
  __half* h1h   = (__half*)h1region;
  float* colbuf = h1region;                       // alias (conv first)
  float* wreg   = h1region + (long)NTOK * 1024;
  __half* w1h   = (__half*)wreg;
  __half* w2h   = (__half*)(wreg + 524288);
  __half* wvh   = (__half*)(wreg + 2 * 524288);
  __half* woh   = (__half*)(wreg + 2 * 524288 + 131072);
  float* Bc     = wreg;                           // alias (conv first)

  dim3 g512(8, 64);
  dim3 glin(2, 64);

  // conv frontend as GEMM
  k_im2col<<<NTOK, 256, 0, stream>>>(spec, colbuf);
  k_wconv<<<688, 256, 0, stream>>>(conv_w, Bc);
  k_gemm<0,0,1,1,0><<<g512, 256, 0, stream>>>(colbuf, nullptr, Bc, conv_b, x1, NTOK, 512, 688);
  k_pe<<<NTOK, 256, 0, stream>>>(pe_row, pe_col, x1, x2);

  for (int l = 0; l < 8; ++l) {
    const long W2 = (long)l * 512 * 512;
    k_ln<2><<<NTOK, 256, 0, stream>>>(x2, lnA_g + l * 512, lnA_b + l * 512, xn, xnh);
    // qk projection stays f32 (feeds hashing)
    k_gemm<1,0,0,0,0><<<g512, 256, 0, stream>>>(xn, nullptr, wqk + W2, nullptr, qkb, NTOK, 512, 512);
    // v projection via f16 MFMA, scattered per head  (512 wg, 2/CU)
    k_tcvt<<<dim3(16, 16), 256, 0, stream>>>(wv + W2, wvh, 512, 512);
    k_mgemm<1,0,0,0><<<512, 256, 0, stream>>>(
        (const ushort*)xnh, (const ushort*)wvh, nullptr, vb16, nullptr, NTOK, 512, 512, 8);
    k_qprep<<<8192, 256, 0, stream>>>(qkb, kn16, qnorm);
    k_hash<<<1024, 256, 0, stream>>>(qkb, rot + (long)l * 8192, buckets);
    k_sort<<<128, 256, 0, stream>>>(buckets, stx);
    k_attn_mfma<<<4096, 256, 0, stream>>>((const ushort*)kn16, qnorm, (const ushort*)vb16,
                                          stx, o16, lg);
    k_combine<<<NTOK, 256, 0, stream>>>(o16, lg, att16);
    // wo projection via f16 MFMA, residual into x1
    k_tcvt<<<dim3(16, 16), 256, 0, stream>>>(wo + W2, woh, 512, 512);
    k_mgemm<0,1,0,1><<<512, 256, 0, stream>>>(
        (const ushort*)att16, (const ushort*)woh, bo + l * 512, nullptr, x1, NTOK, 512, 512, 8);
    // FFN via f16 MFMA
    k_ln<1><<<NTOK, 256, 0, stream>>>(x1, lnF_g + l * 512, lnF_b + l * 512, nullptr, xnh);
    k_tcvt<<<dim3(64, 16), 256, 0, stream>>>(w1 + (long)l * 512 * 2048, w1h, 512, 2048);
    k_mgemm<0,1,1,0><<<2048, 256, 0, stream>>>(
        (const ushort*)xnh, (const ushort*)w1h, b1 + (long)l * 2048, h1h, nullptr, NTOK, 2048, 512, 32);
    k_tcvt<<<dim3(16, 64), 256, 0, stream>>>(w2 + (long)l * 2048 * 512, w2h, 2048, 512);
    k_mgemm<0,1,0,1><<<512, 256, 0, stream>>>(
        (const ushort*)h1h, (const ushort*)w2h, b2 + (long)l * 512, nullptr, x2, NTOK, 512, 2048, 8);
  }
  k_gemm<0,0,1,0,1><<<glin, 256, 0, stream>>>(x1, x2, lin_w, lin_b, (float*)d_out, NTOK, 88, 512);
}

// Round 6
// 1894.532 us; speedup vs baseline: 4.4187x; 1.1609x over previous
//
#include <hip/hip_runtime.h>
#include <hip/hip_fp16.h>
#include <cstdint>

#define T_LEN 2048
#define NTOK  4096      // B*T
#define NHASH 8
#define SELF_VAL -5e4f
#define SPLIT_S 2048.f
#define SPLIT_IS (1.f/2048.f)

typedef __attribute__((ext_vector_type(8))) short short8v;
typedef __attribute__((ext_vector_type(8))) _Float16 half8v;
typedef __attribute__((ext_vector_type(4))) float f32x4;
typedef __attribute__((ext_vector_type(4))) unsigned short ushort4v;

__device__ inline void split16(float v, __half& h1, __half& h2) {
  h1 = __float2half(v);
  h2 = __float2half((v - __half2float(h1)) * SPLIT_S);
}

// ---------------------------------------------------------------- im2col split-f16 (conv k=3 pad=1), K padded to 704
__global__ __launch_bounds__(256) void k_im2col2(
    const float* __restrict__ spec, __half* __restrict__ c1, __half* __restrict__ c2) {
  int m = blockIdx.x; int b = m >> 11, t = m & 2047;
  for (int c = threadIdx.x; c < 704; c += 256) {
    float v = 0.f;
    if (c < 687) {
      int k = (c >= 458) ? 2 : (c >= 229 ? 1 : 0);
      int i = c - k * 229;
      int tt = t + k - 1;
      if (tt >= 0 && tt < T_LEN) v = spec[((long)b * T_LEN + tt) * 229 + i];
    }
    __half h1, h2; split16(v, h1, h2);
    c1[(long)m * 704 + c] = h1; c2[(long)m * 704 + c] = h2;
  }
}

// conv weight split, Bt layout [o][c=k*229+i], c padded to 704
__global__ __launch_bounds__(256) void k_wconv2(
    const float* __restrict__ w, __half* __restrict__ d1, __half* __restrict__ d2) {
  int o = blockIdx.x;
  for (int c = threadIdx.x; c < 704; c += 256) {
    float v = 0.f;
    if (c < 687) {
      int k = (c >= 458) ? 2 : (c >= 229 ? 1 : 0);
      int i = c - k * 229;
      v = w[((long)o * 229 + i) * 3 + k];
    }
    __half h1, h2; split16(v, h1, h2);
    d1[(long)o * 704 + c] = h1; d2[(long)o * 704 + c] = h2;
  }
}

__global__ __launch_bounds__(256) void k_pe(
    const float* __restrict__ pe_row, const float* __restrict__ pe_col,
    float* __restrict__ x1, float* __restrict__ x2) {
  int m = blockIdx.x, t = m & 2047;
  for (int o = threadIdx.x; o < 512; o += 256) {
    long idx = (long)m * 512 + o;
    float v = x1[idx] + ((o < 256) ? pe_row[(t >> 6) * 256 + o]
                                   : pe_col[(t & 63) * 256 + (o - 256)]);
    x1[idx] = v; x2[idx] = v;
  }
}

// ---------------------------------------------------------------- layernorm; SPLIT: also emit scaled f16 correction
template<int SPLIT>
__global__ __launch_bounds__(256) void k_ln(
    const float* __restrict__ x, const float* __restrict__ g,
    const float* __restrict__ bb, __half* __restrict__ o1, __half* __restrict__ o2) {
  int row = blockIdx.x, tid = threadIdx.x;
  const float* xr = x + (long)row * 512;
  float v0 = xr[tid], v1 = xr[tid + 256];
  float s1 = v0 + v1, s2 = v0 * v0 + v1 * v1;
  #pragma unroll
  for (int off = 1; off < 64; off <<= 1) { s1 += __shfl_xor(s1, off); s2 += __shfl_xor(s2, off); }
  __shared__ float r1[4], r2[4];
  int w = tid >> 6, lane = tid & 63;
  if (lane == 0) { r1[w] = s1; r2[w] = s2; }
  __syncthreads();
  float S1 = r1[0] + r1[1] + r1[2] + r1[3];
  float S2 = r2[0] + r2[1] + r2[2] + r2[3];
  float mean = S1 * (1.f / 512.f);
  float var  = S2 * (1.f / 512.f) - mean * mean;
  float rstd = 1.f / sqrtf(var + 1e-5f);
  float a0 = (v0 - mean) * rstd * g[tid] + bb[tid];
  float a1 = (v1 - mean) * rstd * g[tid + 256] + bb[tid + 256];
  if (SPLIT) {
    __half h1, h2;
    split16(a0, h1, h2); o1[(long)row * 512 + tid] = h1; o2[(long)row * 512 + tid] = h2;
    split16(a1, h1, h2); o1[(long)row * 512 + tid + 256] = h1; o2[(long)row * 512 + tid + 256] = h2;
  } else {
    o1[(long)row * 512 + tid]       = __float2half(a0);
    o1[(long)row * 512 + tid + 256] = __float2half(a1);
  }
}

// 0.5*(x1+x2) -> split f16
__global__ __launch_bounds__(256) void k_halfcvt(
    const float* __restrict__ x1, const float* __restrict__ x2,
    __half* __restrict__ a1, __half* __restrict__ a2) {
  long idx = (long)blockIdx.x * 512 + threadIdx.x;
  #pragma unroll
  for (int rep = 0; rep < 2; ++rep, idx += 256) {
    float v = 0.5f * (x1[idx] + x2[idx]);
    __half h1, h2; split16(v, h1, h2);
    a1[idx] = h1; a2[idx] = h2;
  }
}

// ---------------------------------------------------------------- split-f16 MFMA GEMM (f32-grade): qk/conv/lin
// C = (A1 + A2/S) @ (B1 + B2/S)^T, dropping A2B2. 64x64 tile, 1D grid + XCD swizzle.
template<int MAP, int BIAS, int RELU, int NG>
__global__ __launch_bounds__(256) void k_mgemm2(
    const ushort* __restrict__ A1, const ushort* __restrict__ A2,
    const ushort* __restrict__ B1, const ushort* __restrict__ B2,
    const float* __restrict__ bias, float* __restrict__ C,
    int M, int N, int K, int ncol, int Nreal) {
  __shared__ ushort As1[64 * 40], As2[64 * 40], Bs1[64 * 40], Bs2[64 * 40];
  int tid = threadIdx.x;
  int nwg = gridDim.x, q8 = nwg >> 3, wg = blockIdx.x;
  int swz = (wg & 7) * q8 + (wg >> 3);
  int m0 = (swz / ncol) * 64, n0 = (swz % ncol) * 64;
  int wid = tid >> 6, lane = tid & 63;
  int wr = wid >> 1, wc = wid & 1;
  int r = lane & 15, kg = lane >> 4;
  int ar = tid >> 2, ac = tid & 3;
  f32x4 accM[2][2] = {}, accC[2][2] = {};
  for (int k0 = 0; k0 < K; k0 += 32) {
    __syncthreads();
    *(short8v*)&As1[ar * 40 + ac * 8] = *(const short8v*)(A1 + (long)(m0 + ar) * K + k0 + ac * 8);
    *(short8v*)&As2[ar * 40 + ac * 8] = *(const short8v*)(A2 + (long)(m0 + ar) * K + k0 + ac * 8);
    *(short8v*)&Bs1[ar * 40 + ac * 8] = *(const short8v*)(B1 + (long)(n0 + ar) * K + k0 + ac * 8);
    *(short8v*)&Bs2[ar * 40 + ac * 8] = *(const short8v*)(B2 + (long)(n0 + ar) * K + k0 + ac * 8);
    __syncthreads();
    half8v a1[2], a2[2], b1[2], b2[2];
    #pragma unroll
    for (int i = 0; i < 2; ++i) {
      a1[i] = *(const half8v*)&As1[(wr * 32 + i * 16 + r) * 40 + kg * 8];
      a2[i] = *(const half8v*)&As2[(wr * 32 + i * 16 + r) * 40 + kg * 8];
    }
    #pragma unroll
    for (int j = 0; j < 2; ++j) {
      b1[j] = *(const half8v*)&Bs1[(wc * 32 + j * 16 + r) * 40 + kg * 8];
      b2[j] = *(const half8v*)&Bs2[(wc * 32 + j * 16 + r) * 40 + kg * 8];
    }
    #pragma unroll
    for (int i = 0; i < 2; ++i)
      #pragma unroll
      for (int j = 0; j < 2; ++j) {
        accM[i][j] = __builtin_amdgcn_mfma_f32_16x16x32_f16(a1[i], b1[j], accM[i][j], 0, 0, 0);
        accC[i][j] = __builtin_amdgcn_mfma_f32_16x16x32_f16(a1[i], b2[j], accC[i][j], 0, 0, 0);
        accC[i][j] = __builtin_amdgcn_mfma_f32_16x16x32_f16(a2[i], b1[j], accC[i][j], 0, 0, 0);
      }
  }
  #pragma unroll
  for (int i = 0; i < 2; ++i) {
    int mb = m0 + wr * 32 + i * 16 + kg * 4;
    #pragma unroll
    for (int j = 0; j < 2; ++j) {
      int n = n0 + wc * 32 + j * 16 + r;
      if (NG && n >= Nreal) continue;
      float bv = BIAS ? bias[n] : 0.f;
      #pragma unroll
      for (int q = 0; q < 4; ++q) {
        float v = accM[i][j][q] + accC[i][j][q] * SPLIT_IS + bv;
        if (RELU) v = fmaxf(v, 0.f);
        long idx;
        if (MAP == 1) {
          int m = mb + q;
          int b = m >> 11, t = m & 2047, hh = n >> 6, dd = n & 63;
          idx = (((long)(b * 8 + hh)) * T_LEN + t) * 64 + dd;
        } else {
          idx = (long)(mb + q) * Nreal + n;
        }
        C[idx] = v;
      }
    }
  }
}

// ---------------------------------------------------------------- f16 MFMA GEMM (v/wo/FFN), 64x64 tile
template<int MAP, int BIAS, int GELU, int RES>
__global__ __launch_bounds__(256) void k_mgemm(
    const ushort* __restrict__ A, const ushort* __restrict__ Bt,
    const float* __restrict__ bias, __half* __restrict__ Ch,
    float* __restrict__ Cf, int M, int N, int K, int ncol) {
  constexpr int MF = 2, NF = 2;
  __shared__ ushort As[64 * 40];
  __shared__ ushort Bs[64 * 40];
  int tid = threadIdx.x;
  int nwg = gridDim.x, q8 = nwg >> 3, wg = blockIdx.x;
  int swz = (wg & 7) * q8 + (wg >> 3);
  int m0 = (swz / ncol) * 64, n0 = (swz % ncol) * 64;
  int wid = tid >> 6, lane = tid & 63;
  int wr = wid >> 1, wc = wid & 1;
  int r = lane & 15, kg = lane >> 4;
  int ar = tid >> 2, ac = tid & 3;
  f32x4 acc[MF][NF] = {};
  for (int k0 = 0; k0 < K; k0 += 32) {
    __syncthreads();
    *(short8v*)&As[ar * 40 + ac * 8] =
        *(const short8v*)(A + (long)(m0 + ar) * K + k0 + ac * 8);
    *(short8v*)&Bs[ar * 40 + ac * 8] =
        *(const short8v*)(Bt + (long)(n0 + ar) * K + k0 + ac * 8);
    __syncthreads();
    half8v af[MF], bf[NF];
    #pragma unroll
    for (int i = 0; i < MF; ++i)
      af[i] = *(const half8v*)&As[(wr * 32 + i * 16 + r) * 40 + kg * 8];
    #pragma unroll
    for (int j = 0; j < NF; ++j)
      bf[j] = *(const half8v*)&Bs[(wc * 32 + j * 16 + r) * 40 + kg * 8];
    #pragma unroll
    for (int i = 0; i < MF; ++i)
      #pragma unroll
      for (int j = 0; j < NF; ++j)
        acc[i][j] = __builtin_amdgcn_mfma_f32_16x16x32_f16(af[i], bf[j], acc[i][j], 0, 0, 0);
  }
  #pragma unroll
  for (int i = 0; i < MF; ++i) {
    int mb = m0 + wr * 32 + i * 16 + kg * 4;
    #pragma unroll
    for (int j = 0; j < NF; ++j) {
      int n = n0 + wc * 32 + j * 16 + r;
      float bv = BIAS ? bias[n] : 0.f;
      #pragma unroll
      for (int q = 0; q < 4; ++q) {
        float v = acc[i][j][q] + bv;
        if (GELU) v = 0.5f * v * (1.f + erff(v * 0.70710678118654752f));
        long idx;
        if (MAP == 1) {
          int m = mb + q;
          int b = m >> 11, t = m & 2047, hh = n >> 6, dd = n & 63;
          idx = (((long)(b * 8 + hh)) * T_LEN + t) * 64 + dd;
        } else {
          idx = (long)(mb + q) * N + n;
        }
        if (RES) Cf[idx] += v;
        else Ch[idx] = __float2half(v);
      }
    }
  }
}

// tiled transpose + f32->f16 (single): dst[c][r] = h(src[r][c])
__global__ __launch_bounds__(256) void k_tcvt(
    const float* __restrict__ src, __half* __restrict__ dst, int R, int C) {
  __shared__ float tile[32][33];
  int c0 = blockIdx.x * 32, r0 = blockIdx.y * 32;
  int tx = threadIdx.x & 31, ty = threadIdx.x >> 5;
  #pragma unroll
  for (int i = 0; i < 4; ++i)
    tile[ty + i * 8][tx] = src[(long)(r0 + ty + i * 8) * C + c0 + tx];
  __syncthreads();
  #pragma unroll
  for (int i = 0; i < 4; ++i)
    dst[(long)(c0 + ty + i * 8) * R + r0 + tx] = __float2half(tile[tx][ty + i * 8]);
}

// tiled transpose + split f16 pair, col-padded: dst[c][r], c in [0,Cpad)
__global__ __launch_bounds__(256) void k_tcvt2(
    const float* __restrict__ src, __half* __restrict__ d1, __half* __restrict__ d2,
    int R, int C) {
  __shared__ float tile[32][33];
  int c0 = blockIdx.x * 32, r0 = blockIdx.y * 32;
  int tx = threadIdx.x & 31, ty = threadIdx.x >> 5;
  #pragma unroll
  for (int i = 0; i < 4; ++i) {
    int c = c0 + tx;
    tile[ty + i * 8][tx] = (c < C) ? src[(long)(r0 + ty + i * 8) * C + c] : 0.f;
  }
  __syncthreads();
  #pragma unroll
  for (int i = 0; i < 4; ++i) {
    float v = tile[tx][ty + i * 8];
    __half h1, h2; split16(v, h1, h2);
    long o = (long)(c0 + ty + i * 8) * R + r0 + tx;
    d1[o] = h1; d2[o] = h2;
  }
}

// ---------------------------------------------------------------- qk prep: normalized f16 K + f32 row norm
__global__ __launch_bounds__(256) void k_qprep(
    const float* __restrict__ qk, __half* __restrict__ kn, float* __restrict__ qnorm) {
  int row = blockIdx.x * 4 + (threadIdx.x >> 6);
  int d = threadIdx.x & 63;
  float v = qk[(long)row * 64 + d];
  float s2 = v * v;
  #pragma unroll
  for (int off = 1; off < 64; off <<= 1) s2 += __shfl_xor(s2, off);
  float nrm = fmaxf(sqrtf(s2), 1e-12f);
  kn[(long)row * 64 + d] = __float2half(v / nrm);
  if (d == 0) qnorm[row] = nrm;
}

// ---------------------------------------------------------------- LSH hashing (f32)
__global__ __launch_bounds__(256) void k_hash(
    const float* __restrict__ qk, const float* __restrict__ rot,
    int* __restrict__ buckets) {
  int bhid = blockIdx.x >> 6; int t0 = (blockIdx.x & 63) * 32;
  __shared__ float qrow[32][64];
  __shared__ float rl[64][8][20];
  for (int idx = threadIdx.x; idx < 32 * 64; idx += 256) {
    int tok = idx >> 6, f = idx & 63;
    qrow[tok][f] = qk[((long)bhid * T_LEN + t0 + tok) * 64 + f];
  }
  for (int idx = threadIdx.x; idx < 64 * 128; idx += 256) {
    int f = idx >> 7, rem = idx & 127, hh = rem >> 4, ii = rem & 15;
    rl[f][hh][ii] = rot[idx];
  }
  __syncthreads();
  int tok = threadIdx.x >> 3, h = threadIdx.x & 7;
  float acc[16] = {};
  for (int f = 0; f < 64; ++f) {
    float qv = qrow[tok][f];
    #pragma unroll
    for (int i = 0; i < 16; ++i) acc[i] += qv * rl[f][h][i];
  }
  float best = acc[0]; int bi = 0;
  #pragma unroll
  for (int i = 1; i < 16; ++i) if (acc[i] > best) { best = acc[i]; bi = i; }
  #pragma unroll
  for (int i = 0; i < 16; ++i) if (-acc[i] > best) { best = -acc[i]; bi = 16 + i; }
  buckets[((long)bhid * 8 + h) * T_LEN + t0 + tok] = bi;
}

// ---------------------------------------------------------------- stable counting sort
__global__ __launch_bounds__(256) void k_sort(
    const int* __restrict__ buckets, int* __restrict__ st) {
  int bh = blockIdx.x >> 3, h = blockIdx.x & 7;
  const int* bk = buckets + ((long)bh * 8 + h) * T_LEN;
  __shared__ unsigned char lb[2048];
  __shared__ int hist[32], cnt[32];
  __shared__ int whist[4][32];
  if (threadIdx.x < 32) hist[threadIdx.x] = 0;
  __syncthreads();
  for (int p = threadIdx.x; p < 2048; p += 256) {
    int v = bk[p]; lb[p] = (unsigned char)v; atomicAdd(&hist[v], 1);
  }
  __syncthreads();
  if (threadIdx.x == 0) {
    int run = 0;
    for (int i = 0; i < 32; ++i) { cnt[i] = run; run += hist[i]; }
  }
  __syncthreads();
  int lane = threadIdx.x & 63, w = threadIdx.x >> 6;
  unsigned long long mlt = (1ull << lane) - 1ull;
  int* outp = st + (long)bh * (NHASH * T_LEN) + h * T_LEN;
  for (int tile = 0; tile < 8; ++tile) {
    int p = tile * 256 + threadIdx.x;
    int myb = lb[p];
    int wrank = 0;
    for (int bv = 0; bv < 32; ++bv) {
      unsigned long long mm = __ballot(myb == bv);
      if (myb == bv) wrank = __popcll(mm & mlt);
      if (lane == bv) whist[w][bv] = __popcll(mm);
    }
    __syncthreads();
    int off = cnt[myb];
    for (int w2 = 0; w2 < w; ++w2) off += whist[w2][myb];
    outp[off + wrank] = p;
    __syncthreads();
    if (threadIdx.x < 32)
      cnt[threadIdx.x] += whist[0][threadIdx.x] + whist[1][threadIdx.x] +
                          whist[2][threadIdx.x] + whist[3][threadIdx.x];
    __syncthreads();
  }
}

// ---------------------------------------------------------------- MFMA chunked attention (o out f16)
__global__ __launch_bounds__(256) void k_attn_mfma(
    const ushort* __restrict__ kn, const float* __restrict__ qnorm,
    const ushort* __restrict__ vv, const int* __restrict__ st,
    __half* __restrict__ o, float* __restrict__ lg) {
  __shared__ ushort Kb[128 * 72];
  __shared__ ushort Vt[64 * 136];
  __shared__ ushort Ps[64 * 136];
  __shared__ int   kpos[128];
  __shared__ float qn[64];
  int bh = blockIdx.x >> 8, c = blockIdx.x & 255;
  int h = c >> 5, cp = (c + 255) & 255;
  int tid = threadIdx.x, lane = tid & 63, w = tid >> 6;
  int r16 = lane & 15, kg = lane >> 4;
  const int* stb = st + (long)bh * (NHASH * T_LEN);
  if (tid < 128) kpos[tid] = stb[((tid < 64) ? c : cp) * 64 + (tid & 63)];
  __syncthreads();
  if (tid < 64) qn[tid] = qnorm[bh * T_LEN + kpos[tid]];
  const ushort* knb = kn + (long)bh * T_LEN * 64;
  const ushort* vvb = vv + (long)bh * T_LEN * 64;
  for (int idx = tid; idx < 1024; idx += 256) {
    int rr = idx >> 3, p = idx & 7;
    *(short8v*)&Kb[rr * 72 + p * 8] = *(const short8v*)(knb + (long)kpos[rr] * 64 + p * 8);
  }
  {
    int rr = (tid & 63) * 2;
    ushort a[16], b[16];
    *(short8v*)&a[0] = *(const short8v*)(vvb + (long)kpos[rr] * 64 + w * 16);
    *(short8v*)&a[8] = *(const short8v*)(vvb + (long)kpos[rr] * 64 + w * 16 + 8);
    *(short8v*)&b[0] = *(const short8v*)(vvb + (long)kpos[rr + 1] * 64 + w * 16);
    *(short8v*)&b[8] = *(const short8v*)(vvb + (long)kpos[rr + 1] * 64 + w * 16 + 8);
    #pragma unroll
    for (int i = 0; i < 16; ++i) {
      int d = w * 16 + i;
      *(unsigned int*)&Vt[d * 136 + rr] = (unsigned int)a[i] | ((unsigned int)b[i] << 16);
    }
  }
  __syncthreads();
  f32x4 sacc[8] = {};
  #pragma unroll
  for (int ks = 0; ks < 2; ++ks) {
    half8v bfq = *(const half8v*)&Kb[(w * 16 + r16) * 72 + ks * 32 + kg * 8];
    #pragma unroll
    for (int i = 0; i < 8; ++i) {
      half8v af = *(const half8v*)&Kb[(i * 16 + r16) * 72 + ks * 32 + kg * 8];
      sacc[i] = __builtin_amdgcn_mfma_f32_16x16x32_f16(af, bfq, sacc[i], 0, 0, 0);
    }
  }
  int q = w * 16 + r16;
  int qposv = kpos[q];
  float sc = 0.125f * qn[q];
  float vals[8][4];
  float mx = -3.4e38f;
  #pragma unroll
  for (int f = 0; f < 8; ++f)
    #pragma unroll
    for (int e = 0; e < 4; ++e) {
      int kv = f * 16 + kg * 4 + e;
      float v = sacc[f][e] * sc;
      if (kpos[kv] == qposv) v = SELF_VAL;
      vals[f][e] = v;
      mx = fmaxf(mx, v);
    }
  mx = fmaxf(mx, __shfl_xor(mx, 16));
  mx = fmaxf(mx, __shfl_xor(mx, 32));
  float sm = 0.f;
  #pragma unroll
  for (int f = 0; f < 8; ++f)
    #pragma unroll
    for (int e = 0; e < 4; ++e) { vals[f][e] = __expf(vals[f][e] - mx); sm += vals[f][e]; }
  sm += __shfl_xor(sm, 16);
  sm += __shfl_xor(sm, 32);
  float inv = 1.f / sm;
  #pragma unroll
  for (int f = 0; f < 8; ++f) {
    ushort4v pw;
    #pragma unroll
    for (int e = 0; e < 4; ++e) pw[e] = __half_as_ushort(__float2half(vals[f][e] * inv));
    *(ushort4v*)&Ps[q * 136 + f * 16 + kg * 4] = pw;
  }
  if (kg == 0) lg[((long)bh * 8 + h) * T_LEN + qposv] = mx + logf(sm);
  __syncthreads();
  f32x4 oacc[4] = {};
  #pragma unroll
  for (int ks = 0; ks < 4; ++ks) {
    half8v vf = *(const half8v*)&Vt[(w * 16 + r16) * 136 + ks * 32 + kg * 8];
    #pragma unroll
    for (int i = 0; i < 4; ++i) {
      half8v pf = *(const half8v*)&Ps[(i * 16 + r16) * 136 + ks * 32 + kg * 8];
      oacc[i] = __builtin_amdgcn_mfma_f32_16x16x32_f16(pf, vf, oacc[i], 0, 0, 0);
    }
  }
  long ob = ((long)bh * 8 + h) * T_LEN;
  int d = w * 16 + r16;
  #pragma unroll
  for (int i = 0; i < 4; ++i)
    #pragma unroll
    for (int e = 0; e < 4; ++e)
      o[(ob + kpos[i * 16 + kg * 4 + e]) * 64 + d] = __float2half(oacc[i][e]);
}

// ---------------------------------------------------------------- combine hash rounds (f16 in/out)
__global__ __launch_bounds__(256) void k_combine(
    const __half* __restrict__ o, const float* __restrict__ lg, __half* __restrict__ att) {
  int m = blockIdx.x; int b = m >> 11, t = m & 2047;
  int head = threadIdx.x >> 5, d0 = (threadIdx.x & 31) * 2;
  int bh = b * 8 + head;
  const float* lgp = lg + (long)bh * 8 * T_LEN + t;
  float l[8], mx = -3.4e38f;
  #pragma unroll
  for (int hh = 0; hh < 8; ++hh) { l[hh] = lgp[(long)hh * T_LEN]; mx = fmaxf(mx, l[hh]); }
  float sm = 0.f;
  #pragma unroll
  for (int hh = 0; hh < 8; ++hh) { l[hh] = expf(l[hh] - mx); sm += l[hh]; }
  float inv = 1.f / sm;
  float a0 = 0.f, a1 = 0.f;
  #pragma unroll
  for (int hh = 0; hh < 8; ++hh) {
    const __half* op = o + (((long)bh * 8 + hh) * T_LEN + t) * 64 + d0;
    float w_ = l[hh] * inv;
    a0 += w_ * __half2float(op[0]); a1 += w_ * __half2float(op[1]);
  }
  unsigned int u = (unsigned int)__half_as_ushort(__float2half(a0)) |
                   ((unsigned int)__half_as_ushort(__float2half(a1)) << 16);
  *(unsigned int*)&att[(long)m * 512 + head * 64 + d0] = u;
}

// ---------------------------------------------------------------- host
extern "C" void kernel_launch(void* const* d_in, const int* in_sizes, int n_in,
                              void* d_out, int out_size, void* d_ws, size_t ws_size,
                              hipStream_t stream) {
  const float* spec   = (const float*)d_in[0];
  const float* conv_w = (const float*)d_in[1];
  const float* conv_b = (const float*)d_in[2];
  const float* pe_row = (const float*)d_in[3];
  const float* pe_col = (const float*)d_in[4];
  const float* lnA_g  = (const float*)d_in[5];
  const float* lnA_b  = (const float*)d_in[6];
  const float* wqk    = (const float*)d_in[7];
  const float* wv     = (const float*)d_in[8];
  const float* wo     = (const float*)d_in[9];
  const float* bo     = (const float*)d_in[10];
  const float* lnF_g  = (const float*)d_in[11];
  const float* lnF_b  = (const float*)d_in[12];
  const float* w1     = (const float*)d_in[13];
  const float* b1     = (const float*)d_in[14];
  const float* w2     = (const float*)d_in[15];
  const float* b2     = (const float*)d_in[16];
  const float* lin_w  = (const float*)d_in[17];
  const float* lin_b  = (const float*)d_in[18];
  const float* rot    = (const float*)d_in[19];

  float* ws = (float*)d_ws;
  const long TOKF = (long)NTOK * 512;            // 2,097,152
  float* x1   = ws;
  float* x2   = x1 + TOKF;
  float* qkb  = x2 + TOKF;
  float* lg   = qkb + TOKF;                       // 262144
  __half* o16 = (__half*)(lg + 262144);           // 16.78M halves
  int*   stx  = (int*)(o16 + (long)16 * 8 * T_LEN * 64);
  int*   buckets = stx + (long)16 * NHASH * T_LEN;
  float* base = (float*)(buckets + (long)16 * NHASH * T_LEN);
  __half* xnh1  = (__half*)base;                  // TOKF halves each
  __half* xnh2  = (__half*)(base + TOKF / 2);
  __half* att16 = (__half*)(base + 2 * (TOKF / 2));
  __half* vb16  = (__half*)(base + 3 * (TOKF / 2));
  __half* kn16  = (__half*)(base + 4 * (TOKF / 2));
  float* qnorm  = base + 5 * (TOKF / 2);          // 32768
  float* h1region = qnorm + 32768;                // 4.19M floats
  __half* h1h   = (__half*)h1region;
  __half* colh1 = (__half*)h1region;              // alias (conv first): 4096*704 halves
  __half* colh2 = colh1 + (long)4096 * 704;
  float* wreg   = h1region + (long)NTOK * 1024;
  __half* w1h   = (__half*)wreg;                  // 1,048,576 halves
  __half* w2h   = (__half*)(wreg + 524288);
  __half* wqh1  = (__half*)(wreg + 2 * 524288);
  __half* wqh2  = (__half*)(wreg + 2 * 524288 + 131072);
  __half* wvh   = (__half*)(wreg + 2 * 524288 + 2 * 131072);
  __half* woh   = (__half*)(wreg + 2 * 524288 + 3 * 131072);
  __half* linh1 = (__half*)(wreg + 2 * 524288 + 4 * 131072);
  __half* linh2 = (__half*)(wreg + 2 * 524288 + 4 * 131072 + 32768);
  __half* cwh1  = w1h;                            // alias (conv first): 512*704 halves
  __half* cwh2  = w2h;

  // conv frontend: split-f16 MFMA GEMM (f32-grade)
  k_im2col2<<<NTOK, 256, 0, stream>>>(spec, colh1, colh2);
  k_wconv2<<<512, 256, 0, stream>>>(conv_w, cwh1, cwh2);
  k_mgemm2<0,1,1,0><<<512, 256, 0, stream>>>(
      (const ushort*)colh1, (const ushort*)colh2, (const ushort*)cwh1, (const ushort*)cwh2,
      conv_b, x1, NTOK, 512, 704, 8, 512);
  k_pe<<<NTOK, 256, 0, stream>>>(pe_row, pe_col, x1, x2);

  for (int l = 0; l < 8; ++l) {
    const long W2 = (long)l * 512 * 512;
    k_ln<1><<<NTOK, 256, 0, stream>>>(x2, lnA_g + l * 512, lnA_b + l * 512, xnh1, xnh2);
    // qk projection: split-f16 MFMA (f32-grade, feeds hashing)
    k_tcvt2<<<dim3(16, 16), 256, 0, stream>>>(wqk + W2, wqh1, wqh2, 512, 512);
    k_mgemm2<1,0,0,0><<<512, 256, 0, stream>>>(
        (const ushort*)xnh1, (const ushort*)xnh2, (const ushort*)wqh1, (const ushort*)wqh2,
        nullptr, qkb, NTOK, 512, 512, 8, 512);
    // v projection via f16 MFMA, scattered per head
    k_tcvt<<<dim3(16, 16), 256, 0, stream>>>(wv + W2, wvh, 512, 512);
    k_mgemm<1,0,0,0><<<512, 256, 0, stream>>>(
        (const ushort*)xnh1, (const ushort*)wvh, nullptr, vb16, nullptr, NTOK, 512, 512, 8);
    k_qprep<<<8192, 256, 0, stream>>>(qkb, kn16, qnorm);
    k_hash<<<1024, 256, 0, stream>>>(qkb, rot + (long)l * 8192, buckets);
    k_sort<<<128, 256, 0, stream>>>(buckets, stx);
    k_attn_mfma<<<4096, 256, 0, stream>>>((const ushort*)kn16, qnorm, (const ushort*)vb16,
                                          stx, o16, lg);
    k_combine<<<NTOK, 256, 0, stream>>>(o16, lg, att16);
    // wo projection via f16 MFMA, residual into x1
    k_tcvt<<<dim3(16, 16), 256, 0, stream>>>(wo + W2, woh, 512, 512);
    k_mgemm<0,1,0,1><<<512, 256, 0, stream>>>(
        (const ushort*)att16, (const ushort*)woh, bo + l * 512, nullptr, x1, NTOK, 512, 512, 8);
    // FFN via f16 MFMA
    k_ln<0><<<NTOK, 256, 0, stream>>>(x1, lnF_g + l * 512, lnF_b + l * 512, xnh1, nullptr);
    k_tcvt<<<dim3(64, 16), 256, 0, stream>>>(w1 + (long)l * 512 * 2048, w1h, 512, 2048);
    k_mgemm<0,1,1,0><<<2048, 256, 0, stream>>>(
        (const ushort*)xnh1, (const ushort*)w1h, b1 + (long)l * 2048, h1h, nullptr, NTOK, 2048, 512, 32);
    k_tcvt<<<dim3(16, 64), 256, 0, stream>>>(w2 + (long)l * 2048 * 512, w2h, 2048, 512);
    k_mgemm<0,1,0,1><<<512, 256, 0, stream>>>(
        (const ushort*)h1h, (const ushort*)w2h, b2 + (long)l * 512, nullptr, x2, NTOK, 512, 2048, 8);
  }
  // final linear: split-f16 (N padded to 128, real 88)
  k_halfcvt<<<NTOK, 256, 0, stream>>>(x1, x2, xnh1, xnh2);
  k_tcvt2<<<dim3(4, 16), 256, 0, stream>>>(lin_w, linh1, linh2, 512, 88);
  k_mgemm2<0,1,0,1><<<128, 256, 0, stream>>>(
      (const ushort*)xnh1, (const ushort*)xnh2, (const ushort*)linh1, (const ushort*)linh2,
      lin_b, (float*)d_out, NTOK, 128, 512, 2, 88);
}